// Round 3
// baseline (2661.869 us; speedup 1.0000x reference)
//
#include <hip/hip_runtime.h>

#define NUM_USERS 200000
#define NUM_ITEMS 100000
#define DIM 64
#define NUM_EDGES 2000000
#define BATCH 16384
#define NUM_LAYERS 3

// ---------------- kernels ----------------

__global__ void copy_f4_kernel(const float4* __restrict__ src, float4* __restrict__ dst, int n4) {
    int idx = blockIdx.x * blockDim.x + threadIdx.x;
    if (idx < n4) dst[idx] = src[idx];
}

// One wave (64 lanes) per edge; lane = embedding dim.
// Fuses both directions: user_agg[u] += item_emb[i]; item_agg[i] += user_emb[u].
__global__ void scatter_kernel(const int* __restrict__ u_nodes, const int* __restrict__ i_nodes,
                               const float* __restrict__ user_emb, const float* __restrict__ item_emb,
                               float* __restrict__ user_agg, float* __restrict__ item_agg) {
    int e    = (blockIdx.x * blockDim.x + threadIdx.x) >> 6;
    int lane = threadIdx.x & 63;
    if (e >= NUM_EDGES) return;
    int u = u_nodes[e];
    int i = i_nodes[e];
    float vi = item_emb[i * DIM + lane];
    atomicAdd(&user_agg[u * DIM + lane], vi);
    float vu = user_emb[u * DIM + lane];
    atomicAdd(&item_agg[i * DIM + lane], vu);
}

// One wave per row: L2-normalize agg row -> emb row, and accumulate into sum row.
__global__ void normalize_kernel(const float* __restrict__ agg, float* __restrict__ emb,
                                 float* __restrict__ sum, int nrows) {
    int row  = (blockIdx.x * blockDim.x + threadIdx.x) >> 6;
    int lane = threadIdx.x & 63;
    if (row >= nrows) return;
    float v  = agg[row * DIM + lane];
    float ss = v * v;
    #pragma unroll
    for (int o = 32; o > 0; o >>= 1) ss += __shfl_xor(ss, o, 64);
    float norm  = sqrtf(ss);
    float n     = v / fmaxf(norm, 1e-12f);
    emb[row * DIM + lane] = n;
    sum[row * DIM + lane] += n;
}

// One wave per batch element: dot(user_sum[u], item_sum[i]) / 16.
__global__ void final_dot_kernel(const float* __restrict__ user_sum, const float* __restrict__ item_sum,
                                 const int* __restrict__ u_idx, const int* __restrict__ i_idx,
                                 float* __restrict__ out) {
    int b    = (blockIdx.x * blockDim.x + threadIdx.x) >> 6;
    int lane = threadIdx.x & 63;
    if (b >= BATCH) return;
    int u = u_idx[b];
    int i = i_idx[b];
    float p = user_sum[u * DIM + lane] * item_sum[i * DIM + lane];
    #pragma unroll
    for (int o = 32; o > 0; o >>= 1) p += __shfl_xor(p, o, 64);
    if (lane == 0) out[b] = p * (1.0f / ((NUM_LAYERS + 1) * (NUM_LAYERS + 1)));
}

// ---------------- launch ----------------

extern "C" void kernel_launch(void* const* d_in, const int* in_sizes, int n_in,
                              void* d_out, int out_size, void* d_ws, size_t ws_size,
                              hipStream_t stream) {
    const float* user_table = (const float*)d_in[0];
    const float* item_table = (const float*)d_in[1];
    const int*   u_idx      = (const int*)d_in[2];
    const int*   i_idx      = (const int*)d_in[3];
    const int*   edges      = (const int*)d_in[4];
    const int*   u_nodes    = edges;              // edge_index[0]
    const int*   i_nodes    = edges + NUM_EDGES;  // edge_index[1]
    float*       out        = (float*)d_out;

    const size_t NU = (size_t)NUM_USERS * DIM;
    const size_t NI = (size_t)NUM_ITEMS * DIM;

    float* ws   = (float*)d_ws;
    float* usum = ws;
    float* uA   = usum + NU;
    float* uB   = uA + NU;
    float* isum = uB + NU;
    float* iA   = isum + NI;
    float* iB   = iA + NI;

    // init running sums with layer-0 embeddings (the tables themselves)
    {
        int n4u = (int)(NU / 4);
        int n4i = (int)(NI / 4);
        copy_f4_kernel<<<(n4u + 255) / 256, 256, 0, stream>>>((const float4*)user_table, (float4*)usum, n4u);
        copy_f4_kernel<<<(n4i + 255) / 256, 256, 0, stream>>>((const float4*)item_table, (float4*)isum, n4i);
    }

    const float* uprev = user_table;
    const float* iprev = item_table;
    float* ucur = uA;
    float* icur = iA;
    float* ualt = uB;
    float* ialt = iB;

    for (int l = 0; l < NUM_LAYERS; ++l) {
        hipMemsetAsync(ucur, 0, NU * sizeof(float), stream);
        hipMemsetAsync(icur, 0, NI * sizeof(float), stream);

        {
            long long threads = (long long)NUM_EDGES * 64;
            int blocks = (int)((threads + 255) / 256);
            scatter_kernel<<<blocks, 256, 0, stream>>>(u_nodes, i_nodes, uprev, iprev, ucur, icur);
        }
        {
            long long tu = (long long)NUM_USERS * 64;
            normalize_kernel<<<(int)((tu + 255) / 256), 256, 0, stream>>>(ucur, ucur, usum, NUM_USERS);
            long long ti = (long long)NUM_ITEMS * 64;
            normalize_kernel<<<(int)((ti + 255) / 256), 256, 0, stream>>>(icur, icur, isum, NUM_ITEMS);
        }

        uprev = ucur; iprev = icur;
        float* t;
        t = ucur; ucur = ualt; ualt = t;
        t = icur; icur = ialt; ialt = t;
    }

    {
        long long tb = (long long)BATCH * 64;
        final_dot_kernel<<<(int)((tb + 255) / 256), 256, 0, stream>>>(usum, isum, u_idx, i_idx, out);
    }
}

// Round 4
// 1397.493 us; speedup vs baseline: 1.9047x; 1.9047x over previous
//
#include <hip/hip_runtime.h>

#define NUM_USERS 200000
#define NUM_ITEMS 100000
#define DIM 64
#define NUM_EDGES 2000000
#define BATCH 16384
#define NUM_LAYERS 3

#define NU64 ((size_t)NUM_USERS * DIM)
#define NI64 ((size_t)NUM_ITEMS * DIM)

// ---------------- common small kernels ----------------

__global__ void copy_f4_kernel(const float4* __restrict__ src, float4* __restrict__ dst, int n4) {
    int idx = blockIdx.x * blockDim.x + threadIdx.x;
    if (idx < n4) dst[idx] = src[idx];
}

__global__ void final_dot_kernel(const float* __restrict__ user_sum, const float* __restrict__ item_sum,
                                 const int* __restrict__ u_idx, const int* __restrict__ i_idx,
                                 float* __restrict__ out) {
    int b    = (blockIdx.x * blockDim.x + threadIdx.x) >> 6;
    int lane = threadIdx.x & 63;
    if (b >= BATCH) return;
    int u = u_idx[b];
    int i = i_idx[b];
    float p = user_sum[(size_t)u * DIM + lane] * item_sum[(size_t)i * DIM + lane];
    #pragma unroll
    for (int o = 32; o > 0; o >>= 1) p += __shfl_xor(p, o, 64);
    if (lane == 0) out[b] = p * (1.0f / ((NUM_LAYERS + 1) * (NUM_LAYERS + 1)));
}

// ---------------- CSR construction ----------------

__global__ void hist_kernel(const int* __restrict__ un, const int* __restrict__ in_,
                            int* __restrict__ u_cnt, int* __restrict__ i_cnt) {
    int e = blockIdx.x * blockDim.x + threadIdx.x;
    if (e >= NUM_EDGES) return;
    atomicAdd(&u_cnt[un[e]], 1);
    atomicAdd(&i_cnt[in_[e]], 1);
}

// pass1: block sums over 1024-element chunks
__global__ void scan_pass1(const int* __restrict__ cnt, int* __restrict__ bsum, int n) {
    __shared__ int s[256];
    int b = blockIdx.x, t = threadIdx.x;
    int base = b * 1024 + t * 4;
    int v = 0;
    #pragma unroll
    for (int k = 0; k < 4; ++k) if (base + k < n) v += cnt[base + k];
    s[t] = v;
    __syncthreads();
    for (int off = 128; off > 0; off >>= 1) {
        if (t < off) s[t] += s[t + off];
        __syncthreads();
    }
    if (t == 0) bsum[b] = s[0];
}

// pass2: exclusive scan of block sums (n <= 256), single block
__global__ void scan_small_excl(int* __restrict__ data, int n) {
    __shared__ int s[256];
    int t = threadIdx.x;
    int v0 = (t < n) ? data[t] : 0;
    s[t] = v0;
    __syncthreads();
    for (int off = 1; off < 256; off <<= 1) {
        int v = (t >= off) ? s[t - off] : 0;
        __syncthreads();
        s[t] += v;
        __syncthreads();
    }
    if (t < n) data[t] = s[t] - v0;  // exclusive = inclusive - self
}

// pass3: per-element exclusive offsets
__global__ void scan_pass3(const int* __restrict__ cnt, const int* __restrict__ bsum,
                           int* __restrict__ offs, int n) {
    __shared__ int s[256];
    int b = blockIdx.x, t = threadIdx.x;
    int base = b * 1024 + t * 4;
    int v[4];
    int tl = 0;
    #pragma unroll
    for (int k = 0; k < 4; ++k) {
        v[k] = (base + k < n) ? cnt[base + k] : 0;
        tl += v[k];
    }
    s[t] = tl;
    __syncthreads();
    for (int off = 1; off < 256; off <<= 1) {
        int x = (t >= off) ? s[t - off] : 0;
        __syncthreads();
        s[t] += x;
        __syncthreads();
    }
    int run = bsum[b] + s[t] - tl;  // exclusive prefix at my first element
    #pragma unroll
    for (int k = 0; k < 4; ++k) {
        if (base + k < n) { offs[base + k] = run; run += v[k]; }
    }
}

__global__ void tail_kernel(int* __restrict__ u_offs, int* __restrict__ i_offs) {
    if (threadIdx.x == 0) { u_offs[NUM_USERS] = NUM_EDGES; i_offs[NUM_ITEMS] = NUM_EDGES; }
}

__global__ void fill_adj(const int* __restrict__ un, const int* __restrict__ in_,
                         int* __restrict__ u_cur, int* __restrict__ i_cur,
                         int* __restrict__ u_adj, int* __restrict__ i_adj) {
    int e = blockIdx.x * blockDim.x + threadIdx.x;
    if (e >= NUM_EDGES) return;
    int u = un[e], it = in_[e];
    int p = atomicAdd(&u_cur[u], 1);
    u_adj[p] = it;
    int q = atomicAdd(&i_cur[it], 1);
    i_adj[q] = u;
}

// ---------------- fused pull + normalize + sum ----------------
// One wave per output row; handles both sides (users then items) in one grid.
__global__ void pull_norm_kernel(const int* __restrict__ u_offs, const int* __restrict__ u_adj,
                                 const int* __restrict__ i_offs, const int* __restrict__ i_adj,
                                 const float* __restrict__ uprev, const float* __restrict__ iprev,
                                 float* __restrict__ unew, float* __restrict__ inew,
                                 float* __restrict__ usum, float* __restrict__ isum) {
    int w    = (blockIdx.x * blockDim.x + threadIdx.x) >> 6;
    int lane = threadIdx.x & 63;
    const int* offs; const int* adj; const float* src; float* demb; float* dsum; int row;
    if (w < NUM_USERS) {
        row = w; offs = u_offs; adj = u_adj; src = iprev; demb = unew; dsum = usum;
    } else {
        row = w - NUM_USERS;
        if (row >= NUM_ITEMS) return;
        offs = i_offs; adj = i_adj; src = uprev; demb = inew; dsum = isum;
    }
    int start = offs[row], end = offs[row + 1];
    float acc = 0.0f;
    for (int base = start; base < end; base += 64) {
        int rem = end - base;
        int idx = (lane < rem) ? adj[base + lane] : 0;
        int cnt = rem < 64 ? rem : 64;
        for (int j = 0; j < cnt; ++j) {
            int nb = __shfl(idx, j, 64);
            acc += src[(size_t)nb * DIM + lane];
        }
    }
    float ss = acc * acc;
    #pragma unroll
    for (int o = 32; o > 0; o >>= 1) ss += __shfl_xor(ss, o, 64);
    float n = acc / fmaxf(sqrtf(ss), 1e-12f);
    demb[(size_t)row * DIM + lane] = n;
    dsum[(size_t)row * DIM + lane] += n;
}

// ---------------- fallback (atomic scatter) kernels ----------------

__global__ void scatter_kernel(const int* __restrict__ u_nodes, const int* __restrict__ i_nodes,
                               const float* __restrict__ user_emb, const float* __restrict__ item_emb,
                               float* __restrict__ user_agg, float* __restrict__ item_agg) {
    int e    = (blockIdx.x * blockDim.x + threadIdx.x) >> 6;
    int lane = threadIdx.x & 63;
    if (e >= NUM_EDGES) return;
    int u = u_nodes[e];
    int i = i_nodes[e];
    float vi = item_emb[(size_t)i * DIM + lane];
    atomicAdd(&user_agg[(size_t)u * DIM + lane], vi);
    float vu = user_emb[(size_t)u * DIM + lane];
    atomicAdd(&item_agg[(size_t)i * DIM + lane], vu);
}

__global__ void normalize_kernel(const float* __restrict__ agg, float* __restrict__ emb,
                                 float* __restrict__ sum, int nrows) {
    int row  = (blockIdx.x * blockDim.x + threadIdx.x) >> 6;
    int lane = threadIdx.x & 63;
    if (row >= nrows) return;
    float v  = agg[(size_t)row * DIM + lane];
    float ss = v * v;
    #pragma unroll
    for (int o = 32; o > 0; o >>= 1) ss += __shfl_xor(ss, o, 64);
    float n = v / fmaxf(sqrtf(ss), 1e-12f);
    emb[(size_t)row * DIM + lane] = n;
    sum[(size_t)row * DIM + lane] += n;
}

// ---------------- launch ----------------

extern "C" void kernel_launch(void* const* d_in, const int* in_sizes, int n_in,
                              void* d_out, int out_size, void* d_ws, size_t ws_size,
                              hipStream_t stream) {
    const float* user_table = (const float*)d_in[0];
    const float* item_table = (const float*)d_in[1];
    const int*   u_idx      = (const int*)d_in[2];
    const int*   i_idx      = (const int*)d_in[3];
    const int*   edges      = (const int*)d_in[4];
    const int*   u_nodes    = edges;              // edge_index[0]
    const int*   i_nodes    = edges + NUM_EDGES;  // edge_index[1]
    float*       out        = (float*)d_out;

    float* f    = (float*)d_ws;
    float* usum = f;
    float* uA   = usum + NU64;
    float* uB   = uA + NU64;
    float* isum = uB + NU64;
    float* iA   = isum + NI64;
    float* iB   = iA + NI64;

    int* ip     = (int*)(iB + NI64);
    int* u_offs = ip;                    // NUM_USERS + 1
    int* i_offs = u_offs + NUM_USERS + 1;  // NUM_ITEMS + 1
    int* u_cur  = i_offs + NUM_ITEMS + 1;  // NUM_USERS (counts, then cursor)
    int* i_cur  = u_cur + NUM_USERS;       // NUM_ITEMS
    int* u_adj  = i_cur + NUM_ITEMS;       // NUM_EDGES
    int* i_adj  = u_adj + NUM_EDGES;       // NUM_EDGES
    int* bsum   = i_adj + NUM_EDGES;       // 256

    const size_t needed = (size_t)(iB + NI64 - f) * 4 +
                          ((size_t)(NUM_USERS + NUM_ITEMS) * 2 + 2 + 2 * NUM_EDGES + 256) * 4;

    // init running sums with layer-0 embeddings
    {
        int n4u = (int)(NU64 / 4), n4i = (int)(NI64 / 4);
        copy_f4_kernel<<<(n4u + 255) / 256, 256, 0, stream>>>((const float4*)user_table, (float4*)usum, n4u);
        copy_f4_kernel<<<(n4i + 255) / 256, 256, 0, stream>>>((const float4*)item_table, (float4*)isum, n4i);
    }

    if (ws_size >= needed) {
        // ---- CSR build ----
        hipMemsetAsync(u_cur, 0, NUM_USERS * sizeof(int), stream);
        hipMemsetAsync(i_cur, 0, NUM_ITEMS * sizeof(int), stream);
        hist_kernel<<<(NUM_EDGES + 255) / 256, 256, 0, stream>>>(u_nodes, i_nodes, u_cur, i_cur);

        int nb_u = (NUM_USERS + 1023) / 1024;
        int nb_i = (NUM_ITEMS + 1023) / 1024;
        scan_pass1<<<nb_u, 256, 0, stream>>>(u_cur, bsum, NUM_USERS);
        scan_small_excl<<<1, 256, 0, stream>>>(bsum, nb_u);
        scan_pass3<<<nb_u, 256, 0, stream>>>(u_cur, bsum, u_offs, NUM_USERS);
        scan_pass1<<<nb_i, 256, 0, stream>>>(i_cur, bsum, NUM_ITEMS);
        scan_small_excl<<<1, 256, 0, stream>>>(bsum, nb_i);
        scan_pass3<<<nb_i, 256, 0, stream>>>(i_cur, bsum, i_offs, NUM_ITEMS);
        tail_kernel<<<1, 64, 0, stream>>>(u_offs, i_offs);

        hipMemcpyAsync(u_cur, u_offs, NUM_USERS * sizeof(int), hipMemcpyDeviceToDevice, stream);
        hipMemcpyAsync(i_cur, i_offs, NUM_ITEMS * sizeof(int), hipMemcpyDeviceToDevice, stream);
        fill_adj<<<(NUM_EDGES + 255) / 256, 256, 0, stream>>>(u_nodes, i_nodes, u_cur, i_cur, u_adj, i_adj);

        // ---- 3 fused pull layers ----
        const float* uprev = user_table;
        const float* iprev = item_table;
        float* ucur = uA; float* icur = iA;
        float* ualt = uB; float* ialt = iB;
        long long waves = (long long)(NUM_USERS + NUM_ITEMS);
        int blocks = (int)((waves * 64 + 255) / 256);
        for (int l = 0; l < NUM_LAYERS; ++l) {
            pull_norm_kernel<<<blocks, 256, 0, stream>>>(u_offs, u_adj, i_offs, i_adj,
                                                         uprev, iprev, ucur, icur, usum, isum);
            uprev = ucur; iprev = icur;
            float* t;
            t = ucur; ucur = ualt; ualt = t;
            t = icur; icur = ialt; ialt = t;
        }
    } else {
        // ---- fallback: atomic scatter path (fits in 230.4 MB) ----
        const float* uprev = user_table;
        const float* iprev = item_table;
        float* ucur = uA; float* icur = iA;
        float* ualt = uB; float* ialt = iB;
        for (int l = 0; l < NUM_LAYERS; ++l) {
            hipMemsetAsync(ucur, 0, NU64 * sizeof(float), stream);
            hipMemsetAsync(icur, 0, NI64 * sizeof(float), stream);
            long long threads = (long long)NUM_EDGES * 64;
            scatter_kernel<<<(int)((threads + 255) / 256), 256, 0, stream>>>(u_nodes, i_nodes, uprev, iprev, ucur, icur);
            long long tu = (long long)NUM_USERS * 64;
            normalize_kernel<<<(int)((tu + 255) / 256), 256, 0, stream>>>(ucur, ucur, usum, NUM_USERS);
            long long ti = (long long)NUM_ITEMS * 64;
            normalize_kernel<<<(int)((ti + 255) / 256), 256, 0, stream>>>(icur, icur, isum, NUM_ITEMS);
            uprev = ucur; iprev = icur;
            float* t;
            t = ucur; ucur = ualt; ualt = t;
            t = icur; icur = ialt; ialt = t;
        }
    }

    {
        long long tb = (long long)BATCH * 64;
        final_dot_kernel<<<(int)((tb + 255) / 256), 256, 0, stream>>>(usum, isum, u_idx, i_idx, out);
    }
}

// Round 5
// 1102.200 us; speedup vs baseline: 2.4151x; 1.2679x over previous
//
#include <hip/hip_runtime.h>

#define NUM_USERS 200000
#define NUM_ITEMS 100000
#define DIM 64
#define NUM_EDGES 2000000
#define BATCH 16384
#define NUM_LAYERS 3

#define NU64 ((size_t)NUM_USERS * DIM)
#define NI64 ((size_t)NUM_ITEMS * DIM)

// ---------------- common small kernels ----------------

__global__ void copy_f4_kernel(const float4* __restrict__ src, float4* __restrict__ dst, int n4) {
    int idx = blockIdx.x * blockDim.x + threadIdx.x;
    if (idx < n4) dst[idx] = src[idx];
}

__global__ void final_dot_kernel(const float* __restrict__ user_sum, const float* __restrict__ item_sum,
                                 const int* __restrict__ u_idx, const int* __restrict__ i_idx,
                                 float* __restrict__ out) {
    int b    = (blockIdx.x * blockDim.x + threadIdx.x) >> 6;
    int lane = threadIdx.x & 63;
    if (b >= BATCH) return;
    int u = u_idx[b];
    int i = i_idx[b];
    float p = user_sum[(size_t)u * DIM + lane] * item_sum[(size_t)i * DIM + lane];
    #pragma unroll
    for (int o = 32; o > 0; o >>= 1) p += __shfl_xor(p, o, 64);
    if (lane == 0) out[b] = p * (1.0f / ((NUM_LAYERS + 1) * (NUM_LAYERS + 1)));
}

// ---------------- CSR construction ----------------

__global__ void hist_kernel(const int* __restrict__ un, const int* __restrict__ in_,
                            int* __restrict__ u_cnt, int* __restrict__ i_cnt) {
    int e = blockIdx.x * blockDim.x + threadIdx.x;
    if (e >= NUM_EDGES) return;
    atomicAdd(&u_cnt[un[e]], 1);
    atomicAdd(&i_cnt[in_[e]], 1);
}

// pass1: block sums over 1024-element chunks
__global__ void scan_pass1(const int* __restrict__ cnt, int* __restrict__ bsum, int n) {
    __shared__ int s[256];
    int b = blockIdx.x, t = threadIdx.x;
    int base = b * 1024 + t * 4;
    int v = 0;
    #pragma unroll
    for (int k = 0; k < 4; ++k) if (base + k < n) v += cnt[base + k];
    s[t] = v;
    __syncthreads();
    for (int off = 128; off > 0; off >>= 1) {
        if (t < off) s[t] += s[t + off];
        __syncthreads();
    }
    if (t == 0) bsum[b] = s[0];
}

// pass2: exclusive scan of block sums (n <= 256), single block
__global__ void scan_small_excl(int* __restrict__ data, int n) {
    __shared__ int s[256];
    int t = threadIdx.x;
    int v0 = (t < n) ? data[t] : 0;
    s[t] = v0;
    __syncthreads();
    for (int off = 1; off < 256; off <<= 1) {
        int v = (t >= off) ? s[t - off] : 0;
        __syncthreads();
        s[t] += v;
        __syncthreads();
    }
    if (t < n) data[t] = s[t] - v0;  // exclusive = inclusive - self
}

// pass3: per-element exclusive offsets -> offs AND cursor copy
__global__ void scan_pass3(const int* __restrict__ cnt, const int* __restrict__ bsum,
                           int* __restrict__ offs, int* __restrict__ cur, int n) {
    __shared__ int s[256];
    int b = blockIdx.x, t = threadIdx.x;
    int base = b * 1024 + t * 4;
    int v[4];
    int tl = 0;
    #pragma unroll
    for (int k = 0; k < 4; ++k) {
        v[k] = (base + k < n) ? cnt[base + k] : 0;
        tl += v[k];
    }
    s[t] = tl;
    __syncthreads();
    for (int off = 1; off < 256; off <<= 1) {
        int x = (t >= off) ? s[t - off] : 0;
        __syncthreads();
        s[t] += x;
        __syncthreads();
    }
    int run = bsum[b] + s[t] - tl;  // exclusive prefix at my first element
    #pragma unroll
    for (int k = 0; k < 4; ++k) {
        if (base + k < n) { offs[base + k] = run; cur[base + k] = run; run += v[k]; }
    }
}

__global__ void tail_kernel(int* __restrict__ u_offs, int* __restrict__ i_offs) {
    if (threadIdx.x == 0) { u_offs[NUM_USERS] = NUM_EDGES; i_offs[NUM_ITEMS] = NUM_EDGES; }
}

__global__ void fill_adj(const int* __restrict__ un, const int* __restrict__ in_,
                         int* __restrict__ u_cur, int* __restrict__ i_cur,
                         int* __restrict__ u_adj, int* __restrict__ i_adj) {
    int e = blockIdx.x * blockDim.x + threadIdx.x;
    if (e >= NUM_EDGES) return;
    int u = un[e], it = in_[e];
    int p = atomicAdd(&u_cur[u], 1);
    u_adj[p] = it;
    int q = atomicAdd(&i_cur[it], 1);
    i_adj[q] = u;
}

// ---------------- fused pull + normalize + sum ----------------
// One wave per output row; 4-way unrolled neighbor loop for memory-level parallelism.
__global__ void pull_norm_kernel(const int* __restrict__ u_offs, const int* __restrict__ u_adj,
                                 const int* __restrict__ i_offs, const int* __restrict__ i_adj,
                                 const float* __restrict__ uprev, const float* __restrict__ iprev,
                                 float* __restrict__ unew, float* __restrict__ inew,
                                 float* __restrict__ usum, float* __restrict__ isum,
                                 int write_emb) {
    int w    = (blockIdx.x * blockDim.x + threadIdx.x) >> 6;
    int lane = threadIdx.x & 63;
    const int* offs; const int* adj; const float* src; float* demb; float* dsum; int row;
    if (w < NUM_USERS) {
        row = w; offs = u_offs; adj = u_adj; src = iprev; demb = unew; dsum = usum;
    } else {
        row = w - NUM_USERS;
        if (row >= NUM_ITEMS) return;
        offs = i_offs; adj = i_adj; src = uprev; demb = inew; dsum = isum;
    }
    int start = offs[row], end = offs[row + 1];
    float acc = 0.0f;
    for (int base = start; base < end; base += 64) {
        int rem = end - base;
        if (rem > 64) rem = 64;
        int idx = (lane < rem) ? adj[base + lane] : 0;
        int j = 0;
        for (; j + 4 <= rem; j += 4) {
            int nb0 = __shfl(idx, j, 64);
            int nb1 = __shfl(idx, j + 1, 64);
            int nb2 = __shfl(idx, j + 2, 64);
            int nb3 = __shfl(idx, j + 3, 64);
            float v0 = src[(size_t)nb0 * DIM + lane];
            float v1 = src[(size_t)nb1 * DIM + lane];
            float v2 = src[(size_t)nb2 * DIM + lane];
            float v3 = src[(size_t)nb3 * DIM + lane];
            acc += v0 + v1 + v2 + v3;
        }
        for (; j < rem; ++j) {
            int nb = __shfl(idx, j, 64);
            acc += src[(size_t)nb * DIM + lane];
        }
    }
    float ss = acc * acc;
    #pragma unroll
    for (int o = 32; o > 0; o >>= 1) ss += __shfl_xor(ss, o, 64);
    float n = acc / fmaxf(sqrtf(ss), 1e-12f);
    if (write_emb) demb[(size_t)row * DIM + lane] = n;
    dsum[(size_t)row * DIM + lane] += n;
}

// ---------------- fallback (atomic scatter) kernels ----------------

__global__ void scatter_kernel(const int* __restrict__ u_nodes, const int* __restrict__ i_nodes,
                               const float* __restrict__ user_emb, const float* __restrict__ item_emb,
                               float* __restrict__ user_agg, float* __restrict__ item_agg) {
    int e    = (blockIdx.x * blockDim.x + threadIdx.x) >> 6;
    int lane = threadIdx.x & 63;
    if (e >= NUM_EDGES) return;
    int u = u_nodes[e];
    int i = i_nodes[e];
    float vi = item_emb[(size_t)i * DIM + lane];
    atomicAdd(&user_agg[(size_t)u * DIM + lane], vi);
    float vu = user_emb[(size_t)u * DIM + lane];
    atomicAdd(&item_agg[(size_t)i * DIM + lane], vu);
}

__global__ void normalize_kernel(const float* __restrict__ agg, float* __restrict__ emb,
                                 float* __restrict__ sum, int nrows) {
    int row  = (blockIdx.x * blockDim.x + threadIdx.x) >> 6;
    int lane = threadIdx.x & 63;
    if (row >= nrows) return;
    float v  = agg[(size_t)row * DIM + lane];
    float ss = v * v;
    #pragma unroll
    for (int o = 32; o > 0; o >>= 1) ss += __shfl_xor(ss, o, 64);
    float n = v / fmaxf(sqrtf(ss), 1e-12f);
    emb[(size_t)row * DIM + lane] = n;
    sum[(size_t)row * DIM + lane] += n;
}

// ---------------- launch ----------------

extern "C" void kernel_launch(void* const* d_in, const int* in_sizes, int n_in,
                              void* d_out, int out_size, void* d_ws, size_t ws_size,
                              hipStream_t stream) {
    const float* user_table = (const float*)d_in[0];
    const float* item_table = (const float*)d_in[1];
    const int*   u_idx      = (const int*)d_in[2];
    const int*   i_idx      = (const int*)d_in[3];
    const int*   edges      = (const int*)d_in[4];
    const int*   u_nodes    = edges;              // edge_index[0]
    const int*   i_nodes    = edges + NUM_EDGES;  // edge_index[1]
    float*       out        = (float*)d_out;

    float* f    = (float*)d_ws;
    float* usum = f;
    float* uA   = usum + NU64;
    float* uB   = uA + NU64;
    float* isum = uB + NU64;
    float* iA   = isum + NI64;
    float* iB   = iA + NI64;

    int* ip     = (int*)(iB + NI64);
    int* u_offs = ip;                      // NUM_USERS + 1
    int* i_offs = u_offs + NUM_USERS + 1;  // NUM_ITEMS + 1
    int* u_cur  = i_offs + NUM_ITEMS + 1;  // NUM_USERS (counts, then cursor)
    int* i_cur  = u_cur + NUM_USERS;       // NUM_ITEMS
    int* u_adj  = i_cur + NUM_ITEMS;       // NUM_EDGES
    int* i_adj  = u_adj + NUM_EDGES;       // NUM_EDGES
    int* bsum   = i_adj + NUM_EDGES;       // 256

    const size_t needed = (size_t)(iB + NI64 - f) * 4 +
                          ((size_t)(NUM_USERS + NUM_ITEMS) * 2 + 2 + 2 * NUM_EDGES + 256) * 4;

    // init running sums with layer-0 embeddings
    {
        int n4u = (int)(NU64 / 4), n4i = (int)(NI64 / 4);
        copy_f4_kernel<<<(n4u + 255) / 256, 256, 0, stream>>>((const float4*)user_table, (float4*)usum, n4u);
        copy_f4_kernel<<<(n4i + 255) / 256, 256, 0, stream>>>((const float4*)item_table, (float4*)isum, n4i);
    }

    if (ws_size >= needed) {
        // ---- CSR build ----
        hipMemsetAsync(u_cur, 0, NUM_USERS * sizeof(int), stream);
        hipMemsetAsync(i_cur, 0, NUM_ITEMS * sizeof(int), stream);
        hist_kernel<<<(NUM_EDGES + 255) / 256, 256, 0, stream>>>(u_nodes, i_nodes, u_cur, i_cur);

        int nb_u = (NUM_USERS + 1023) / 1024;
        int nb_i = (NUM_ITEMS + 1023) / 1024;
        scan_pass1<<<nb_u, 256, 0, stream>>>(u_cur, bsum, NUM_USERS);
        scan_small_excl<<<1, 256, 0, stream>>>(bsum, nb_u);
        scan_pass3<<<nb_u, 256, 0, stream>>>(u_cur, bsum, u_offs, u_cur, NUM_USERS);
        scan_pass1<<<nb_i, 256, 0, stream>>>(i_cur, bsum, NUM_ITEMS);
        scan_small_excl<<<1, 256, 0, stream>>>(bsum, nb_i);
        scan_pass3<<<nb_i, 256, 0, stream>>>(i_cur, bsum, i_offs, i_cur, NUM_ITEMS);
        tail_kernel<<<1, 64, 0, stream>>>(u_offs, i_offs);

        fill_adj<<<(NUM_EDGES + 255) / 256, 256, 0, stream>>>(u_nodes, i_nodes, u_cur, i_cur, u_adj, i_adj);

        // ---- 3 fused pull layers ----
        const float* uprev = user_table;
        const float* iprev = item_table;
        float* ucur = uA; float* icur = iA;
        float* ualt = uB; float* ialt = iB;
        long long waves = (long long)(NUM_USERS + NUM_ITEMS);
        int blocks = (int)((waves * 64 + 255) / 256);
        for (int l = 0; l < NUM_LAYERS; ++l) {
            int write_emb = (l < NUM_LAYERS - 1) ? 1 : 0;
            pull_norm_kernel<<<blocks, 256, 0, stream>>>(u_offs, u_adj, i_offs, i_adj,
                                                         uprev, iprev, ucur, icur, usum, isum,
                                                         write_emb);
            uprev = ucur; iprev = icur;
            float* t;
            t = ucur; ucur = ualt; ualt = t;
            t = icur; icur = ialt; ialt = t;
        }
    } else {
        // ---- fallback: atomic scatter path ----
        const float* uprev = user_table;
        const float* iprev = item_table;
        float* ucur = uA; float* icur = iA;
        float* ualt = uB; float* ialt = iB;
        for (int l = 0; l < NUM_LAYERS; ++l) {
            hipMemsetAsync(ucur, 0, NU64 * sizeof(float), stream);
            hipMemsetAsync(icur, 0, NI64 * sizeof(float), stream);
            long long threads = (long long)NUM_EDGES * 64;
            scatter_kernel<<<(int)((threads + 255) / 256), 256, 0, stream>>>(u_nodes, i_nodes, uprev, iprev, ucur, icur);
            long long tu = (long long)NUM_USERS * 64;
            normalize_kernel<<<(int)((tu + 255) / 256), 256, 0, stream>>>(ucur, ucur, usum, NUM_USERS);
            long long ti = (long long)NUM_ITEMS * 64;
            normalize_kernel<<<(int)((ti + 255) / 256), 256, 0, stream>>>(icur, icur, isum, NUM_ITEMS);
            uprev = ucur; iprev = icur;
            float* t;
            t = ucur; ucur = ualt; ualt = t;
            t = icur; icur = ialt; ialt = t;
        }
    }

    {
        long long tb = (long long)BATCH * 64;
        final_dot_kernel<<<(int)((tb + 255) / 256), 256, 0, stream>>>(usum, isum, u_idx, i_idx, out);
    }
}

// Round 6
// 808.768 us; speedup vs baseline: 3.2913x; 1.3628x over previous
//
#include <hip/hip_runtime.h>

#define NUM_USERS 200000
#define NUM_ITEMS 100000
#define DIM 64
#define NUM_EDGES 2000000
#define BATCH 16384
#define NUM_LAYERS 3

#define NU64 ((size_t)NUM_USERS * DIM)
#define NI64 ((size_t)NUM_ITEMS * DIM)

// bucketed CSR fill: user buckets = 2048-node ranges, item buckets = 1024-node ranges
#define RU_SHIFT 11
#define RI_SHIFT 10
#define NBU 98   // ceil(200000 / 2048)
#define NBI 98   // ceil(100000 / 1024)

// ---------------- common small kernels ----------------

__global__ void copy_f4_kernel(const float4* __restrict__ src, float4* __restrict__ dst, int n4) {
    int idx = blockIdx.x * blockDim.x + threadIdx.x;
    if (idx < n4) dst[idx] = src[idx];
}

__global__ void final_dot_kernel(const float* __restrict__ user_sum, const float* __restrict__ item_sum,
                                 const int* __restrict__ u_idx, const int* __restrict__ i_idx,
                                 float* __restrict__ out) {
    int b    = (blockIdx.x * blockDim.x + threadIdx.x) >> 6;
    int lane = threadIdx.x & 63;
    if (b >= BATCH) return;
    int u = u_idx[b];
    int i = i_idx[b];
    float p = user_sum[(size_t)u * DIM + lane] * item_sum[(size_t)i * DIM + lane];
    #pragma unroll
    for (int o = 32; o > 0; o >>= 1) p += __shfl_xor(p, o, 64);
    if (lane == 0) out[b] = p * (1.0f / ((NUM_LAYERS + 1) * (NUM_LAYERS + 1)));
}

// ---------------- CSR construction ----------------

__global__ void hist_kernel(const int* __restrict__ un, const int* __restrict__ in_,
                            int* __restrict__ u_cnt, int* __restrict__ i_cnt) {
    int e = blockIdx.x * blockDim.x + threadIdx.x;
    if (e >= NUM_EDGES) return;
    atomicAdd(&u_cnt[un[e]], 1);
    atomicAdd(&i_cnt[in_[e]], 1);
}

__global__ void scan_pass1(const int* __restrict__ cnt, int* __restrict__ bsum, int n) {
    __shared__ int s[256];
    int b = blockIdx.x, t = threadIdx.x;
    int base = b * 1024 + t * 4;
    int v = 0;
    #pragma unroll
    for (int k = 0; k < 4; ++k) if (base + k < n) v += cnt[base + k];
    s[t] = v;
    __syncthreads();
    for (int off = 128; off > 0; off >>= 1) {
        if (t < off) s[t] += s[t + off];
        __syncthreads();
    }
    if (t == 0) bsum[b] = s[0];
}

__global__ void scan_small_excl(int* __restrict__ data, int n) {
    __shared__ int s[256];
    int t = threadIdx.x;
    int v0 = (t < n) ? data[t] : 0;
    s[t] = v0;
    __syncthreads();
    for (int off = 1; off < 256; off <<= 1) {
        int v = (t >= off) ? s[t - off] : 0;
        __syncthreads();
        s[t] += v;
        __syncthreads();
    }
    if (t < n) data[t] = s[t] - v0;
}

__global__ void scan_pass3(const int* __restrict__ cnt, const int* __restrict__ bsum,
                           int* __restrict__ offs, int n) {
    __shared__ int s[256];
    int b = blockIdx.x, t = threadIdx.x;
    int base = b * 1024 + t * 4;
    int v[4];
    int tl = 0;
    #pragma unroll
    for (int k = 0; k < 4; ++k) {
        v[k] = (base + k < n) ? cnt[base + k] : 0;
        tl += v[k];
    }
    s[t] = tl;
    __syncthreads();
    for (int off = 1; off < 256; off <<= 1) {
        int x = (t >= off) ? s[t - off] : 0;
        __syncthreads();
        s[t] += x;
        __syncthreads();
    }
    int run = bsum[b] + s[t] - tl;
    #pragma unroll
    for (int k = 0; k < 4; ++k) {
        if (base + k < n) { offs[base + k] = run; run += v[k]; }
    }
}

__global__ void tail_kernel(int* __restrict__ u_offs, int* __restrict__ i_offs) {
    if (threadIdx.x == 0) { u_offs[NUM_USERS] = NUM_EDGES; i_offs[NUM_ITEMS] = NUM_EDGES; }
}

// Pass A: LDS-binned bucket scatter of (node, val) records into per-bucket staging.
// 2048 edges per block, burst-writes per bucket for write-combining.
__global__ void bucket_scatter(const int* __restrict__ un, const int* __restrict__ in_,
                               const int* __restrict__ u_offs, const int* __restrict__ i_offs,
                               int* __restrict__ gcurU, int* __restrict__ gcurI,
                               int2* __restrict__ stageU, int2* __restrict__ stageI) {
    __shared__ int cntU[NBU], cntI[NBI];
    __shared__ int baseU[NBU], baseI[NBI];
    int t = threadIdx.x;
    if (t < NBU) cntU[t] = 0;
    if (t < NBI) cntI[t] = 0;
    __syncthreads();
    int e0 = blockIdx.x * 2048 + t;
    int u[8], it[8], bu[8], bi[8], ru[8], ri[8];
    bool valid[8];
    #pragma unroll
    for (int k = 0; k < 8; ++k) {
        int e = e0 + k * 256;
        valid[k] = (e < NUM_EDGES);
        if (valid[k]) {
            u[k]  = un[e];
            it[k] = in_[e];
            bu[k] = u[k]  >> RU_SHIFT;
            bi[k] = it[k] >> RI_SHIFT;
            ru[k] = atomicAdd(&cntU[bu[k]], 1);
            ri[k] = atomicAdd(&cntI[bi[k]], 1);
        }
    }
    __syncthreads();
    if (t < NBU) baseU[t] = u_offs[t << RU_SHIFT] + atomicAdd(&gcurU[t], cntU[t]);
    if (t < NBI) baseI[t] = i_offs[t << RI_SHIFT] + atomicAdd(&gcurI[t], cntI[t]);
    __syncthreads();
    #pragma unroll
    for (int k = 0; k < 8; ++k) {
        if (valid[k]) {
            stageU[baseU[bu[k]] + ru[k]] = make_int2(u[k], it[k]);
            stageI[baseI[bi[k]] + ri[k]] = make_int2(it[k], u[k]);
        }
    }
}

// Pass B: one block per bucket; LDS cursors place records into the bucket's
// contiguous adj range (L2-local writes, no global atomics).
__global__ void bucket_place(const int* __restrict__ u_offs, const int* __restrict__ i_offs,
                             const int2* __restrict__ stageU, const int2* __restrict__ stageI,
                             int* __restrict__ u_adj, int* __restrict__ i_adj) {
    __shared__ int offs_l[2049];
    __shared__ int cur[2048];
    int b = blockIdx.x, t = threadIdx.x;
    const int* offs; const int2* stage; int* adj; int lo, range;
    if (b < NBU) {
        offs = u_offs; stage = stageU; adj = u_adj;
        lo = b << RU_SHIFT;
        range = NUM_USERS - lo; if (range > 2048) range = 2048;
    } else {
        int bb = b - NBU;
        offs = i_offs; stage = stageI; adj = i_adj;
        lo = bb << RI_SHIFT;
        range = NUM_ITEMS - lo; if (range > 1024) range = 1024;
    }
    for (int k = t; k < range + 1; k += blockDim.x) offs_l[k] = offs[lo + k];
    for (int k = t; k < range; k += blockDim.x) cur[k] = 0;
    __syncthreads();
    int rlo = offs_l[0], rhi = offs_l[range];
    for (int r = rlo + t; r < rhi; r += blockDim.x) {
        int2 rec = stage[r];
        int loc = rec.x - lo;
        int p = atomicAdd(&cur[loc], 1);
        adj[offs_l[loc] + p] = rec.y;
    }
}

// ---------------- fused pull + normalize + sum ----------------

__global__ void pull_norm_kernel(const int* __restrict__ u_offs, const int* __restrict__ u_adj,
                                 const int* __restrict__ i_offs, const int* __restrict__ i_adj,
                                 const float* __restrict__ uprev, const float* __restrict__ iprev,
                                 float* __restrict__ unew, float* __restrict__ inew,
                                 float* __restrict__ usum, float* __restrict__ isum,
                                 int write_emb) {
    int w    = (blockIdx.x * blockDim.x + threadIdx.x) >> 6;
    int lane = threadIdx.x & 63;
    const int* offs; const int* adj; const float* src; float* demb; float* dsum; int row;
    if (w < NUM_USERS) {
        row = w; offs = u_offs; adj = u_adj; src = iprev; demb = unew; dsum = usum;
    } else {
        row = w - NUM_USERS;
        if (row >= NUM_ITEMS) return;
        offs = i_offs; adj = i_adj; src = uprev; demb = inew; dsum = isum;
    }
    int start = offs[row], end = offs[row + 1];
    float acc = 0.0f;
    for (int base = start; base < end; base += 64) {
        int rem = end - base;
        if (rem > 64) rem = 64;
        int idx = (lane < rem) ? adj[base + lane] : 0;
        int j = 0;
        for (; j + 8 <= rem; j += 8) {
            int nb0 = __shfl(idx, j, 64);
            int nb1 = __shfl(idx, j + 1, 64);
            int nb2 = __shfl(idx, j + 2, 64);
            int nb3 = __shfl(idx, j + 3, 64);
            int nb4 = __shfl(idx, j + 4, 64);
            int nb5 = __shfl(idx, j + 5, 64);
            int nb6 = __shfl(idx, j + 6, 64);
            int nb7 = __shfl(idx, j + 7, 64);
            float v0 = src[(size_t)nb0 * DIM + lane];
            float v1 = src[(size_t)nb1 * DIM + lane];
            float v2 = src[(size_t)nb2 * DIM + lane];
            float v3 = src[(size_t)nb3 * DIM + lane];
            float v4 = src[(size_t)nb4 * DIM + lane];
            float v5 = src[(size_t)nb5 * DIM + lane];
            float v6 = src[(size_t)nb6 * DIM + lane];
            float v7 = src[(size_t)nb7 * DIM + lane];
            acc += ((v0 + v1) + (v2 + v3)) + ((v4 + v5) + (v6 + v7));
        }
        for (; j + 4 <= rem; j += 4) {
            int nb0 = __shfl(idx, j, 64);
            int nb1 = __shfl(idx, j + 1, 64);
            int nb2 = __shfl(idx, j + 2, 64);
            int nb3 = __shfl(idx, j + 3, 64);
            float v0 = src[(size_t)nb0 * DIM + lane];
            float v1 = src[(size_t)nb1 * DIM + lane];
            float v2 = src[(size_t)nb2 * DIM + lane];
            float v3 = src[(size_t)nb3 * DIM + lane];
            acc += (v0 + v1) + (v2 + v3);
        }
        for (; j < rem; ++j) {
            int nb = __shfl(idx, j, 64);
            acc += src[(size_t)nb * DIM + lane];
        }
    }
    float ss = acc * acc;
    #pragma unroll
    for (int o = 32; o > 0; o >>= 1) ss += __shfl_xor(ss, o, 64);
    float n = acc / fmaxf(sqrtf(ss), 1e-12f);
    if (write_emb) demb[(size_t)row * DIM + lane] = n;
    dsum[(size_t)row * DIM + lane] += n;
}

// ---------------- fallback (atomic scatter) kernels ----------------

__global__ void scatter_kernel(const int* __restrict__ u_nodes, const int* __restrict__ i_nodes,
                               const float* __restrict__ user_emb, const float* __restrict__ item_emb,
                               float* __restrict__ user_agg, float* __restrict__ item_agg) {
    int e    = (blockIdx.x * blockDim.x + threadIdx.x) >> 6;
    int lane = threadIdx.x & 63;
    if (e >= NUM_EDGES) return;
    int u = u_nodes[e];
    int i = i_nodes[e];
    float vi = item_emb[(size_t)i * DIM + lane];
    atomicAdd(&user_agg[(size_t)u * DIM + lane], vi);
    float vu = user_emb[(size_t)u * DIM + lane];
    atomicAdd(&item_agg[(size_t)i * DIM + lane], vu);
}

__global__ void normalize_kernel(const float* __restrict__ agg, float* __restrict__ emb,
                                 float* __restrict__ sum, int nrows) {
    int row  = (blockIdx.x * blockDim.x + threadIdx.x) >> 6;
    int lane = threadIdx.x & 63;
    if (row >= nrows) return;
    float v  = agg[(size_t)row * DIM + lane];
    float ss = v * v;
    #pragma unroll
    for (int o = 32; o > 0; o >>= 1) ss += __shfl_xor(ss, o, 64);
    float n = v / fmaxf(sqrtf(ss), 1e-12f);
    emb[(size_t)row * DIM + lane] = n;
    sum[(size_t)row * DIM + lane] += n;
}

// ---------------- launch ----------------

extern "C" void kernel_launch(void* const* d_in, const int* in_sizes, int n_in,
                              void* d_out, int out_size, void* d_ws, size_t ws_size,
                              hipStream_t stream) {
    const float* user_table = (const float*)d_in[0];
    const float* item_table = (const float*)d_in[1];
    const int*   u_idx      = (const int*)d_in[2];
    const int*   i_idx      = (const int*)d_in[3];
    const int*   edges      = (const int*)d_in[4];
    const int*   u_nodes    = edges;              // edge_index[0]
    const int*   i_nodes    = edges + NUM_EDGES;  // edge_index[1]
    float*       out        = (float*)d_out;

    float* f    = (float*)d_ws;
    float* usum = f;
    float* uA   = usum + NU64;
    float* uB   = uA + NU64;
    float* isum = uB + NU64;
    float* iA   = isum + NI64;
    float* iB   = iA + NI64;

    int* ip     = (int*)(iB + NI64);
    int* u_offs = ip;                      // NUM_USERS + 1
    int* i_offs = u_offs + NUM_USERS + 1;  // NUM_ITEMS + 1
    int* u_cnt  = i_offs + NUM_ITEMS + 1;  // NUM_USERS
    int* i_cnt  = u_cnt + NUM_USERS;       // NUM_ITEMS
    int* u_adj  = i_cnt + NUM_ITEMS;       // NUM_EDGES
    int* i_adj  = u_adj + NUM_EDGES;       // NUM_EDGES
    int* bsum   = i_adj + NUM_EDGES;       // 256
    int* gcurU  = bsum + 256;              // NBU
    int* gcurI  = gcurU + NBU;             // NBI

    // staging (pass A->B records) reuses the idle uB/iB ping-pong buffers:
    // needed 16 MB each; uB is 51.2 MB, iB is 25.6 MB. 8B-aligned (even float offsets).
    int2* stageU = (int2*)uB;
    int2* stageI = (int2*)iB;

    const size_t needed = (size_t)(iB + NI64 - f) * 4 +
                          ((size_t)(NUM_USERS + NUM_ITEMS) * 2 + 2 + 2 * NUM_EDGES + 256 + NBU + NBI) * 4;

    // init running sums with layer-0 embeddings
    {
        int n4u = (int)(NU64 / 4), n4i = (int)(NI64 / 4);
        copy_f4_kernel<<<(n4u + 255) / 256, 256, 0, stream>>>((const float4*)user_table, (float4*)usum, n4u);
        copy_f4_kernel<<<(n4i + 255) / 256, 256, 0, stream>>>((const float4*)item_table, (float4*)isum, n4i);
    }

    if (ws_size >= needed) {
        // ---- CSR build ----
        hipMemsetAsync(u_cnt, 0, (size_t)(NUM_USERS + NUM_ITEMS) * sizeof(int), stream);
        hipMemsetAsync(gcurU, 0, (NBU + NBI) * sizeof(int), stream);
        hist_kernel<<<(NUM_EDGES + 255) / 256, 256, 0, stream>>>(u_nodes, i_nodes, u_cnt, i_cnt);

        int nb_u = (NUM_USERS + 1023) / 1024;
        int nb_i = (NUM_ITEMS + 1023) / 1024;
        scan_pass1<<<nb_u, 256, 0, stream>>>(u_cnt, bsum, NUM_USERS);
        scan_small_excl<<<1, 256, 0, stream>>>(bsum, nb_u);
        scan_pass3<<<nb_u, 256, 0, stream>>>(u_cnt, bsum, u_offs, NUM_USERS);
        scan_pass1<<<nb_i, 256, 0, stream>>>(i_cnt, bsum, NUM_ITEMS);
        scan_small_excl<<<1, 256, 0, stream>>>(bsum, nb_i);
        scan_pass3<<<nb_i, 256, 0, stream>>>(i_cnt, bsum, i_offs, NUM_ITEMS);
        tail_kernel<<<1, 64, 0, stream>>>(u_offs, i_offs);

        int nblkA = (NUM_EDGES + 2047) / 2048;
        bucket_scatter<<<nblkA, 256, 0, stream>>>(u_nodes, i_nodes, u_offs, i_offs,
                                                  gcurU, gcurI, stageU, stageI);
        bucket_place<<<NBU + NBI, 256, 0, stream>>>(u_offs, i_offs, stageU, stageI, u_adj, i_adj);

        // ---- 3 fused pull layers ----
        const float* uprev = user_table;
        const float* iprev = item_table;
        float* ucur = uA; float* icur = iA;
        float* ualt = uB; float* ialt = iB;
        long long waves = (long long)(NUM_USERS + NUM_ITEMS);
        int blocks = (int)((waves * 64 + 255) / 256);
        for (int l = 0; l < NUM_LAYERS; ++l) {
            int write_emb = (l < NUM_LAYERS - 1) ? 1 : 0;
            pull_norm_kernel<<<blocks, 256, 0, stream>>>(u_offs, u_adj, i_offs, i_adj,
                                                         uprev, iprev, ucur, icur, usum, isum,
                                                         write_emb);
            uprev = ucur; iprev = icur;
            float* t;
            t = ucur; ucur = ualt; ualt = t;
            t = icur; icur = ialt; ialt = t;
        }
    } else {
        // ---- fallback: atomic scatter path ----
        const float* uprev = user_table;
        const float* iprev = item_table;
        float* ucur = uA; float* icur = iA;
        float* ualt = uB; float* ialt = iB;
        for (int l = 0; l < NUM_LAYERS; ++l) {
            hipMemsetAsync(ucur, 0, NU64 * sizeof(float), stream);
            hipMemsetAsync(icur, 0, NI64 * sizeof(float), stream);
            long long threads = (long long)NUM_EDGES * 64;
            scatter_kernel<<<(int)((threads + 255) / 256), 256, 0, stream>>>(u_nodes, i_nodes, uprev, iprev, ucur, icur);
            long long tu = (long long)NUM_USERS * 64;
            normalize_kernel<<<(int)((tu + 255) / 256), 256, 0, stream>>>(ucur, ucur, usum, NUM_USERS);
            long long ti = (long long)NUM_ITEMS * 64;
            normalize_kernel<<<(int)((ti + 255) / 256), 256, 0, stream>>>(icur, icur, isum, NUM_ITEMS);
            uprev = ucur; iprev = icur;
            float* t;
            t = ucur; ucur = ualt; ualt = t;
            t = icur; icur = ialt; ialt = t;
        }
    }

    {
        long long tb = (long long)BATCH * 64;
        final_dot_kernel<<<(int)((tb + 255) / 256), 256, 0, stream>>>(usum, isum, u_idx, i_idx, out);
    }
}

// Round 7
// 805.916 us; speedup vs baseline: 3.3029x; 1.0035x over previous
//
#include <hip/hip_runtime.h>

#define NUM_USERS 200000
#define NUM_ITEMS 100000
#define DIM 64
#define NUM_EDGES 2000000
#define BATCH 16384
#define NUM_LAYERS 3

#define NU64 ((size_t)NUM_USERS * DIM)
#define NI64 ((size_t)NUM_ITEMS * DIM)

// bucketed CSR fill: user buckets = 2048-node ranges, item buckets = 1024-node ranges
#define RU_SHIFT 11
#define RI_SHIFT 10
#define NBU 98   // ceil(200000 / 2048)
#define NBI 98   // ceil(100000 / 1024)

// ---------------- common small kernels ----------------

__global__ void copy_f4_kernel(const float4* __restrict__ src, float4* __restrict__ dst, int n4) {
    int idx = blockIdx.x * blockDim.x + threadIdx.x;
    if (idx < n4) dst[idx] = src[idx];
}

__global__ void final_dot_kernel(const float* __restrict__ user_sum, const float* __restrict__ item_sum,
                                 const int* __restrict__ u_idx, const int* __restrict__ i_idx,
                                 float* __restrict__ out) {
    int b    = (blockIdx.x * blockDim.x + threadIdx.x) >> 6;
    int lane = threadIdx.x & 63;
    if (b >= BATCH) return;
    int u = u_idx[b];
    int i = i_idx[b];
    float p = user_sum[(size_t)u * DIM + lane] * item_sum[(size_t)i * DIM + lane];
    #pragma unroll
    for (int o = 32; o > 0; o >>= 1) p += __shfl_xor(p, o, 64);
    if (lane == 0) out[b] = p * (1.0f / ((NUM_LAYERS + 1) * (NUM_LAYERS + 1)));
}

// ---------------- CSR construction ----------------

__global__ void hist_kernel(const int* __restrict__ un, const int* __restrict__ in_,
                            int* __restrict__ u_cnt, int* __restrict__ i_cnt) {
    int e = blockIdx.x * blockDim.x + threadIdx.x;
    if (e >= NUM_EDGES) return;
    atomicAdd(&u_cnt[un[e]], 1);
    atomicAdd(&i_cnt[in_[e]], 1);
}

__global__ void scan_pass1(const int* __restrict__ cnt, int* __restrict__ bsum, int n) {
    __shared__ int s[256];
    int b = blockIdx.x, t = threadIdx.x;
    int base = b * 1024 + t * 4;
    int v = 0;
    #pragma unroll
    for (int k = 0; k < 4; ++k) if (base + k < n) v += cnt[base + k];
    s[t] = v;
    __syncthreads();
    for (int off = 128; off > 0; off >>= 1) {
        if (t < off) s[t] += s[t + off];
        __syncthreads();
    }
    if (t == 0) bsum[b] = s[0];
}

__global__ void scan_small_excl(int* __restrict__ data, int n) {
    __shared__ int s[256];
    int t = threadIdx.x;
    int v0 = (t < n) ? data[t] : 0;
    s[t] = v0;
    __syncthreads();
    for (int off = 1; off < 256; off <<= 1) {
        int v = (t >= off) ? s[t - off] : 0;
        __syncthreads();
        s[t] += v;
        __syncthreads();
    }
    if (t < n) data[t] = s[t] - v0;
}

__global__ void scan_pass3(const int* __restrict__ cnt, const int* __restrict__ bsum,
                           int* __restrict__ offs, int n) {
    __shared__ int s[256];
    int b = blockIdx.x, t = threadIdx.x;
    int base = b * 1024 + t * 4;
    int v[4];
    int tl = 0;
    #pragma unroll
    for (int k = 0; k < 4; ++k) {
        v[k] = (base + k < n) ? cnt[base + k] : 0;
        tl += v[k];
    }
    s[t] = tl;
    __syncthreads();
    for (int off = 1; off < 256; off <<= 1) {
        int x = (t >= off) ? s[t - off] : 0;
        __syncthreads();
        s[t] += x;
        __syncthreads();
    }
    int run = bsum[b] + s[t] - tl;
    #pragma unroll
    for (int k = 0; k < 4; ++k) {
        if (base + k < n) { offs[base + k] = run; run += v[k]; }
    }
}

__global__ void tail_kernel(int* __restrict__ u_offs, int* __restrict__ i_offs) {
    if (threadIdx.x == 0) { u_offs[NUM_USERS] = NUM_EDGES; i_offs[NUM_ITEMS] = NUM_EDGES; }
}

// Pass A: LDS-binned bucket scatter of (node, val) records into per-bucket staging.
__global__ void bucket_scatter(const int* __restrict__ un, const int* __restrict__ in_,
                               const int* __restrict__ u_offs, const int* __restrict__ i_offs,
                               int* __restrict__ gcurU, int* __restrict__ gcurI,
                               int2* __restrict__ stageU, int2* __restrict__ stageI) {
    __shared__ int cntU[NBU], cntI[NBI];
    __shared__ int baseU[NBU], baseI[NBI];
    int t = threadIdx.x;
    if (t < NBU) cntU[t] = 0;
    if (t < NBI) cntI[t] = 0;
    __syncthreads();
    int e0 = blockIdx.x * 2048 + t;
    int u[8], it[8], bu[8], bi[8], ru[8], ri[8];
    bool valid[8];
    #pragma unroll
    for (int k = 0; k < 8; ++k) {
        int e = e0 + k * 256;
        valid[k] = (e < NUM_EDGES);
        if (valid[k]) {
            u[k]  = un[e];
            it[k] = in_[e];
            bu[k] = u[k]  >> RU_SHIFT;
            bi[k] = it[k] >> RI_SHIFT;
            ru[k] = atomicAdd(&cntU[bu[k]], 1);
            ri[k] = atomicAdd(&cntI[bi[k]], 1);
        }
    }
    __syncthreads();
    if (t < NBU) baseU[t] = u_offs[t << RU_SHIFT] + atomicAdd(&gcurU[t], cntU[t]);
    if (t < NBI) baseI[t] = i_offs[t << RI_SHIFT] + atomicAdd(&gcurI[t], cntI[t]);
    __syncthreads();
    #pragma unroll
    for (int k = 0; k < 8; ++k) {
        if (valid[k]) {
            stageU[baseU[bu[k]] + ru[k]] = make_int2(u[k], it[k]);
            stageI[baseI[bi[k]] + ri[k]] = make_int2(it[k], u[k]);
        }
    }
}

// Pass B: one block per bucket; LDS cursors place records into the bucket's
// contiguous adj range (L2-local writes, no global atomics). 1024 threads.
__global__ void bucket_place(const int* __restrict__ u_offs, const int* __restrict__ i_offs,
                             const int2* __restrict__ stageU, const int2* __restrict__ stageI,
                             int* __restrict__ u_adj, int* __restrict__ i_adj) {
    __shared__ int offs_l[2049];
    __shared__ int cur[2048];
    int b = blockIdx.x, t = threadIdx.x;
    const int* offs; const int2* stage; int* adj; int lo, range;
    if (b < NBU) {
        offs = u_offs; stage = stageU; adj = u_adj;
        lo = b << RU_SHIFT;
        range = NUM_USERS - lo; if (range > 2048) range = 2048;
    } else {
        int bb = b - NBU;
        offs = i_offs; stage = stageI; adj = i_adj;
        lo = bb << RI_SHIFT;
        range = NUM_ITEMS - lo; if (range > 1024) range = 1024;
    }
    for (int k = t; k < range + 1; k += blockDim.x) offs_l[k] = offs[lo + k];
    for (int k = t; k < range; k += blockDim.x) cur[k] = 0;
    __syncthreads();
    int rlo = offs_l[0], rhi = offs_l[range];
    for (int r = rlo + t; r < rhi; r += blockDim.x) {
        int2 rec = stage[r];
        int loc = rec.x - lo;
        int p = atomicAdd(&cur[loc], 1);
        adj[offs_l[loc] + p] = rec.y;
    }
}

// ---------------- fused pull + normalize + sum ----------------
// One wave per row; lanes 0-31 process neighbor j, lanes 32-63 neighbor j+1,
// each lane loads float2 (8B) -> half the loads/shuffles/addr-math per byte.
__global__ void pull_norm_kernel(const int* __restrict__ u_offs, const int* __restrict__ u_adj,
                                 const int* __restrict__ i_offs, const int* __restrict__ i_adj,
                                 const float* __restrict__ uprev, const float* __restrict__ iprev,
                                 float* __restrict__ unew, float* __restrict__ inew,
                                 float* __restrict__ usum, float* __restrict__ isum,
                                 int write_emb) {
    int w    = (blockIdx.x * blockDim.x + threadIdx.x) >> 6;
    int lane = threadIdx.x & 63;
    int half = lane >> 5;   // 0 or 1
    int l32  = lane & 31;
    const int* offs; const int* adj; const float* src; float* demb; float* dsum; int row;
    if (w < NUM_USERS) {
        row = w; offs = u_offs; adj = u_adj; src = iprev; demb = unew; dsum = usum;
    } else {
        row = w - NUM_USERS;
        if (row >= NUM_ITEMS) return;
        offs = i_offs; adj = i_adj; src = uprev; demb = inew; dsum = isum;
    }
    int start = offs[row], end = offs[row + 1];
    int cnt = end - start;
    float ax = 0.0f, ay = 0.0f;
    for (int base = 0; base < cnt; base += 64) {
        int rem = cnt - base;
        if (rem > 64) rem = 64;
        int idx = (lane < rem) ? adj[start + base + lane] : 0;
        int j = 0;
        // 4 pairs (8 neighbors) per unrolled iteration
        for (; j + 8 <= rem; j += 8) {
            #pragma unroll
            for (int p = 0; p < 4; ++p) {
                int nb = __shfl(idx, j + 2 * p + half, 64);
                const float2* srow = (const float2*)(src + (size_t)nb * DIM);
                float2 v = srow[l32];
                ax += v.x; ay += v.y;
            }
        }
        for (; j + 2 <= rem; j += 2) {
            int nb = __shfl(idx, j + half, 64);
            const float2* srow = (const float2*)(src + (size_t)nb * DIM);
            float2 v = srow[l32];
            ax += v.x; ay += v.y;
        }
        if (j < rem) {  // odd leftover neighbor: lanes 0-31 only
            int nb = __shfl(idx, j, 64);
            const float2* srow = (const float2*)(src + (size_t)nb * DIM);
            float2 v = srow[l32];
            if (half == 0) { ax += v.x; ay += v.y; }
        }
    }
    // merge the two half-wave partial sums
    ax += __shfl_xor(ax, 32, 64);
    ay += __shfl_xor(ay, 32, 64);
    float ss = ax * ax + ay * ay;
    #pragma unroll
    for (int o = 16; o > 0; o >>= 1) ss += __shfl_xor(ss, o, 64);
    float inv = 1.0f / fmaxf(sqrtf(ss), 1e-12f);
    float2 n2 = make_float2(ax * inv, ay * inv);
    if (half == 0) {
        if (write_emb) ((float2*)(demb + (size_t)row * DIM))[l32] = n2;
        float2* ds = (float2*)(dsum + (size_t)row * DIM);
        float2 old = ds[l32];
        ds[l32] = make_float2(old.x + n2.x, old.y + n2.y);
    }
}

// ---------------- fallback (atomic scatter) kernels ----------------

__global__ void scatter_kernel(const int* __restrict__ u_nodes, const int* __restrict__ i_nodes,
                               const float* __restrict__ user_emb, const float* __restrict__ item_emb,
                               float* __restrict__ user_agg, float* __restrict__ item_agg) {
    int e    = (blockIdx.x * blockDim.x + threadIdx.x) >> 6;
    int lane = threadIdx.x & 63;
    if (e >= NUM_EDGES) return;
    int u = u_nodes[e];
    int i = i_nodes[e];
    float vi = item_emb[(size_t)i * DIM + lane];
    atomicAdd(&user_agg[(size_t)u * DIM + lane], vi);
    float vu = user_emb[(size_t)u * DIM + lane];
    atomicAdd(&item_agg[(size_t)i * DIM + lane], vu);
}

__global__ void normalize_kernel(const float* __restrict__ agg, float* __restrict__ emb,
                                 float* __restrict__ sum, int nrows) {
    int row  = (blockIdx.x * blockDim.x + threadIdx.x) >> 6;
    int lane = threadIdx.x & 63;
    if (row >= nrows) return;
    float v  = agg[(size_t)row * DIM + lane];
    float ss = v * v;
    #pragma unroll
    for (int o = 32; o > 0; o >>= 1) ss += __shfl_xor(ss, o, 64);
    float n = v / fmaxf(sqrtf(ss), 1e-12f);
    emb[(size_t)row * DIM + lane] = n;
    sum[(size_t)row * DIM + lane] += n;
}

// ---------------- launch ----------------

extern "C" void kernel_launch(void* const* d_in, const int* in_sizes, int n_in,
                              void* d_out, int out_size, void* d_ws, size_t ws_size,
                              hipStream_t stream) {
    const float* user_table = (const float*)d_in[0];
    const float* item_table = (const float*)d_in[1];
    const int*   u_idx      = (const int*)d_in[2];
    const int*   i_idx      = (const int*)d_in[3];
    const int*   edges      = (const int*)d_in[4];
    const int*   u_nodes    = edges;              // edge_index[0]
    const int*   i_nodes    = edges + NUM_EDGES;  // edge_index[1]
    float*       out        = (float*)d_out;

    float* f    = (float*)d_ws;
    float* usum = f;
    float* uA   = usum + NU64;
    float* uB   = uA + NU64;
    float* isum = uB + NU64;
    float* iA   = isum + NI64;
    float* iB   = iA + NI64;

    int* ip     = (int*)(iB + NI64);
    int* u_offs = ip;                      // NUM_USERS + 1
    int* i_offs = u_offs + NUM_USERS + 1;  // NUM_ITEMS + 1
    int* u_cnt  = i_offs + NUM_ITEMS + 1;  // NUM_USERS
    int* i_cnt  = u_cnt + NUM_USERS;       // NUM_ITEMS
    int* u_adj  = i_cnt + NUM_ITEMS;       // NUM_EDGES
    int* i_adj  = u_adj + NUM_EDGES;       // NUM_EDGES
    int* bsum   = i_adj + NUM_EDGES;       // 256
    int* gcurU  = bsum + 256;              // NBU
    int* gcurI  = gcurU + NBU;             // NBI

    // staging (pass A->B records) reuses the idle uB/iB ping-pong buffers
    int2* stageU = (int2*)uB;
    int2* stageI = (int2*)iB;

    const size_t needed = (size_t)(iB + NI64 - f) * 4 +
                          ((size_t)(NUM_USERS + NUM_ITEMS) * 2 + 2 + 2 * NUM_EDGES + 256 + NBU + NBI) * 4;

    // init running sums with layer-0 embeddings
    {
        int n4u = (int)(NU64 / 4), n4i = (int)(NI64 / 4);
        copy_f4_kernel<<<(n4u + 255) / 256, 256, 0, stream>>>((const float4*)user_table, (float4*)usum, n4u);
        copy_f4_kernel<<<(n4i + 255) / 256, 256, 0, stream>>>((const float4*)item_table, (float4*)isum, n4i);
    }

    if (ws_size >= needed) {
        // ---- CSR build ----
        hipMemsetAsync(u_cnt, 0, (size_t)(NUM_USERS + NUM_ITEMS) * sizeof(int), stream);
        hipMemsetAsync(gcurU, 0, (NBU + NBI) * sizeof(int), stream);
        hist_kernel<<<(NUM_EDGES + 255) / 256, 256, 0, stream>>>(u_nodes, i_nodes, u_cnt, i_cnt);

        int nb_u = (NUM_USERS + 1023) / 1024;
        int nb_i = (NUM_ITEMS + 1023) / 1024;
        scan_pass1<<<nb_u, 256, 0, stream>>>(u_cnt, bsum, NUM_USERS);
        scan_small_excl<<<1, 256, 0, stream>>>(bsum, nb_u);
        scan_pass3<<<nb_u, 256, 0, stream>>>(u_cnt, bsum, u_offs, NUM_USERS);
        scan_pass1<<<nb_i, 256, 0, stream>>>(i_cnt, bsum, NUM_ITEMS);
        scan_small_excl<<<1, 256, 0, stream>>>(bsum, nb_i);
        scan_pass3<<<nb_i, 256, 0, stream>>>(i_cnt, bsum, i_offs, NUM_ITEMS);
        tail_kernel<<<1, 64, 0, stream>>>(u_offs, i_offs);

        int nblkA = (NUM_EDGES + 2047) / 2048;
        bucket_scatter<<<nblkA, 256, 0, stream>>>(u_nodes, i_nodes, u_offs, i_offs,
                                                  gcurU, gcurI, stageU, stageI);
        bucket_place<<<NBU + NBI, 1024, 0, stream>>>(u_offs, i_offs, stageU, stageI, u_adj, i_adj);

        // ---- 3 fused pull layers ----
        const float* uprev = user_table;
        const float* iprev = item_table;
        float* ucur = uA; float* icur = iA;
        float* ualt = uB; float* ialt = iB;
        long long waves = (long long)(NUM_USERS + NUM_ITEMS);
        int blocks = (int)((waves * 64 + 255) / 256);
        for (int l = 0; l < NUM_LAYERS; ++l) {
            int write_emb = (l < NUM_LAYERS - 1) ? 1 : 0;
            pull_norm_kernel<<<blocks, 256, 0, stream>>>(u_offs, u_adj, i_offs, i_adj,
                                                         uprev, iprev, ucur, icur, usum, isum,
                                                         write_emb);
            uprev = ucur; iprev = icur;
            float* t;
            t = ucur; ucur = ualt; ualt = t;
            t = icur; icur = ialt; ialt = t;
        }
    } else {
        // ---- fallback: atomic scatter path ----
        const float* uprev = user_table;
        const float* iprev = item_table;
        float* ucur = uA; float* icur = iA;
        float* ualt = uB; float* ialt = iB;
        for (int l = 0; l < NUM_LAYERS; ++l) {
            hipMemsetAsync(ucur, 0, NU64 * sizeof(float), stream);
            hipMemsetAsync(icur, 0, NI64 * sizeof(float), stream);
            long long threads = (long long)NUM_EDGES * 64;
            scatter_kernel<<<(int)((threads + 255) / 256), 256, 0, stream>>>(u_nodes, i_nodes, uprev, iprev, ucur, icur);
            long long tu = (long long)NUM_USERS * 64;
            normalize_kernel<<<(int)((tu + 255) / 256), 256, 0, stream>>>(ucur, ucur, usum, NUM_USERS);
            long long ti = (long long)NUM_ITEMS * 64;
            normalize_kernel<<<(int)((ti + 255) / 256), 256, 0, stream>>>(icur, icur, isum, NUM_ITEMS);
            uprev = ucur; iprev = icur;
            float* t;
            t = ucur; ucur = ualt; ualt = t;
            t = icur; icur = ialt; ialt = t;
        }
    }

    {
        long long tb = (long long)BATCH * 64;
        final_dot_kernel<<<(int)((tb + 255) / 256), 256, 0, stream>>>(usum, isum, u_idx, i_idx, out);
    }
}

// Round 10
// 769.559 us; speedup vs baseline: 3.4590x; 1.0472x over previous
//
#include <hip/hip_runtime.h>

#define NUM_USERS 200000
#define NUM_ITEMS 100000
#define DIM 64
#define NUM_EDGES 2000000
#define BATCH 16384
#define NUM_LAYERS 3

#define NU64 ((size_t)NUM_USERS * DIM)
#define NI64 ((size_t)NUM_ITEMS * DIM)

// bucketed CSR fill: user buckets = 2048-node ranges, item buckets = 1024-node ranges
#define RU_SHIFT 11
#define RI_SHIFT 10
#define NBU 98   // ceil(200000 / 2048)
#define NBI 98   // ceil(100000 / 1024)
#define CAPU 24576  // fixed staging capacity per bucket (expected ~20480, 28-sigma margin)
#define CAPI 24576

// ---------------- final dot ----------------

__global__ void final_dot_kernel(const float* __restrict__ user_sum, const float* __restrict__ item_sum,
                                 const int* __restrict__ u_idx, const int* __restrict__ i_idx,
                                 float* __restrict__ out) {
    int b    = (blockIdx.x * blockDim.x + threadIdx.x) >> 6;
    int lane = threadIdx.x & 63;
    if (b >= BATCH) return;
    int u = u_idx[b];
    int i = i_idx[b];
    float p = user_sum[(size_t)u * DIM + lane] * item_sum[(size_t)i * DIM + lane];
    #pragma unroll
    for (int o = 32; o > 0; o >>= 1) p += __shfl_xor(p, o, 64);
    if (lane == 0) out[b] = p * (1.0f / ((NUM_LAYERS + 1) * (NUM_LAYERS + 1)));
}

// ---------------- CSR construction ----------------

__global__ void scan_pass1(const int* __restrict__ cnt, int* __restrict__ bsum, int n) {
    __shared__ int s[256];
    int b = blockIdx.x, t = threadIdx.x;
    int base = b * 1024 + t * 4;
    int v = 0;
    #pragma unroll
    for (int k = 0; k < 4; ++k) if (base + k < n) v += cnt[base + k];
    s[t] = v;
    __syncthreads();
    for (int off = 128; off > 0; off >>= 1) {
        if (t < off) s[t] += s[t + off];
        __syncthreads();
    }
    if (t == 0) bsum[b] = s[0];
}

__global__ void scan_small_excl(int* __restrict__ data, int n) {
    __shared__ int s[256];
    int t = threadIdx.x;
    int v0 = (t < n) ? data[t] : 0;
    s[t] = v0;
    __syncthreads();
    for (int off = 1; off < 256; off <<= 1) {
        int v = (t >= off) ? s[t - off] : 0;
        __syncthreads();
        s[t] += v;
        __syncthreads();
    }
    if (t < n) data[t] = s[t] - v0;
}

__global__ void scan_pass3(const int* __restrict__ cnt, const int* __restrict__ bsum,
                           int* __restrict__ offs, int n) {
    __shared__ int s[256];
    int b = blockIdx.x, t = threadIdx.x;
    int base = b * 1024 + t * 4;
    int v[4];
    int tl = 0;
    #pragma unroll
    for (int k = 0; k < 4; ++k) {
        v[k] = (base + k < n) ? cnt[base + k] : 0;
        tl += v[k];
    }
    s[t] = tl;
    __syncthreads();
    for (int off = 1; off < 256; off <<= 1) {
        int x = (t >= off) ? s[t - off] : 0;
        __syncthreads();
        s[t] += x;
        __syncthreads();
    }
    int run = bsum[b] + s[t] - tl;
    #pragma unroll
    for (int k = 0; k < 4; ++k) {
        if (base + k < n) { offs[base + k] = run; run += v[k]; }
    }
}

__global__ void tail_kernel(int* __restrict__ u_offs, int* __restrict__ i_offs) {
    if (threadIdx.x == 0) { u_offs[NUM_USERS] = NUM_EDGES; i_offs[NUM_ITEMS] = NUM_EDGES; }
}

// Pass A: LDS-binned bucket scatter into FIXED-capacity per-bucket staging,
// with the per-node histogram fused in (no separate hist pass, no u_offs dep).
__global__ void bucket_scatter(const int* __restrict__ un, const int* __restrict__ in_,
                               int* __restrict__ u_cnt, int* __restrict__ i_cnt,
                               int* __restrict__ gcurU, int* __restrict__ gcurI,
                               int2* __restrict__ stageU, int2* __restrict__ stageI) {
    __shared__ int cntU[NBU], cntI[NBI];
    __shared__ int baseU[NBU], baseI[NBI];
    int t = threadIdx.x;
    if (t < NBU) cntU[t] = 0;
    if (t < NBI) cntI[t] = 0;
    __syncthreads();
    int e0 = blockIdx.x * 2048 + t;
    int u[8], it[8], bu[8], bi[8], ru[8], ri[8];
    bool valid[8];
    #pragma unroll
    for (int k = 0; k < 8; ++k) {
        int e = e0 + k * 256;
        valid[k] = (e < NUM_EDGES);
        if (valid[k]) {
            u[k]  = un[e];
            it[k] = in_[e];
            atomicAdd(&u_cnt[u[k]], 1);   // fused per-node histogram
            atomicAdd(&i_cnt[it[k]], 1);
            bu[k] = u[k]  >> RU_SHIFT;
            bi[k] = it[k] >> RI_SHIFT;
            ru[k] = atomicAdd(&cntU[bu[k]], 1);
            ri[k] = atomicAdd(&cntI[bi[k]], 1);
        }
    }
    __syncthreads();
    if (t < NBU) baseU[t] = t * CAPU + atomicAdd(&gcurU[t], cntU[t]);
    if (t < NBI) baseI[t] = t * CAPI + atomicAdd(&gcurI[t], cntI[t]);
    __syncthreads();
    #pragma unroll
    for (int k = 0; k < 8; ++k) {
        if (valid[k]) {
            stageU[baseU[bu[k]] + ru[k]] = make_int2(u[k], it[k]);
            stageI[baseI[bi[k]] + ri[k]] = make_int2(it[k], u[k]);
        }
    }
}

// Pass B: one block per bucket; LDS cursors place records (L2-local, no global atomics).
__global__ void bucket_place(const int* __restrict__ u_offs, const int* __restrict__ i_offs,
                             const int* __restrict__ gcurU, const int* __restrict__ gcurI,
                             const int2* __restrict__ stageU, const int2* __restrict__ stageI,
                             int* __restrict__ u_adj, int* __restrict__ i_adj) {
    __shared__ int offs_l[2049];
    __shared__ int cur[2048];
    int b = blockIdx.x, t = threadIdx.x;
    const int* offs; const int2* stage; int* adj; int lo, range, nrec;
    if (b < NBU) {
        offs = u_offs; adj = u_adj;
        stage = stageU + (size_t)b * CAPU;
        nrec  = gcurU[b];
        lo = b << RU_SHIFT;
        range = NUM_USERS - lo; if (range > 2048) range = 2048;
    } else {
        int bb = b - NBU;
        offs = i_offs; adj = i_adj;
        stage = stageI + (size_t)bb * CAPI;
        nrec  = gcurI[bb];
        lo = bb << RI_SHIFT;
        range = NUM_ITEMS - lo; if (range > 1024) range = 1024;
    }
    for (int k = t; k < range + 1; k += blockDim.x) offs_l[k] = offs[lo + k];
    for (int k = t; k < range; k += blockDim.x) cur[k] = 0;
    __syncthreads();
    for (int r = t; r < nrec; r += blockDim.x) {
        int2 rec = stage[r];
        int loc = rec.x - lo;
        int p = atomicAdd(&cur[loc], 1);
        adj[offs_l[loc] + p] = rec.y;
    }
}

// ---------------- fused pull + normalize + sum (r7-proven float2 structure) ----------------
// One wave per row; lanes 0-31 process neighbor j, lanes 32-63 neighbor j+1,
// each lane loads float2 (8B). Layer 0 (init_sum) seeds the running sum from
// the original table row instead of reading dsum.
__global__ void pull_norm_kernel(const int* __restrict__ u_offs, const int* __restrict__ u_adj,
                                 const int* __restrict__ i_offs, const int* __restrict__ i_adj,
                                 const float* __restrict__ uprev, const float* __restrict__ iprev,
                                 float* __restrict__ unew, float* __restrict__ inew,
                                 float* __restrict__ usum, float* __restrict__ isum,
                                 const float* __restrict__ uown, const float* __restrict__ iown,
                                 int write_emb, int init_sum) {
    int w    = (blockIdx.x * blockDim.x + threadIdx.x) >> 6;
    int lane = threadIdx.x & 63;
    int half = lane >> 5;   // 0 or 1
    int l32  = lane & 31;
    const int* offs; const int* adj; const float* src; float* demb; float* dsum; const float* own; int row;
    if (w < NUM_USERS) {
        row = w; offs = u_offs; adj = u_adj; src = iprev; demb = unew; dsum = usum; own = uown;
    } else {
        row = w - NUM_USERS;
        if (row >= NUM_ITEMS) return;
        offs = i_offs; adj = i_adj; src = uprev; demb = inew; dsum = isum; own = iown;
    }
    int start = offs[row], end = offs[row + 1];
    int cnt = end - start;
    float ax = 0.0f, ay = 0.0f;
    for (int base = 0; base < cnt; base += 64) {
        int rem = cnt - base;
        if (rem > 64) rem = 64;
        int idx = (lane < rem) ? adj[start + base + lane] : 0;
        int j = 0;
        // 4 pairs (8 neighbors) per unrolled iteration
        for (; j + 8 <= rem; j += 8) {
            #pragma unroll
            for (int p = 0; p < 4; ++p) {
                int nb = __shfl(idx, j + 2 * p + half, 64);
                const float2* srow = (const float2*)(src + (size_t)nb * DIM);
                float2 v = srow[l32];
                ax += v.x; ay += v.y;
            }
        }
        for (; j + 2 <= rem; j += 2) {
            int nb = __shfl(idx, j + half, 64);
            const float2* srow = (const float2*)(src + (size_t)nb * DIM);
            float2 v = srow[l32];
            ax += v.x; ay += v.y;
        }
        if (j < rem) {  // odd leftover neighbor: lanes 0-31 only
            int nb = __shfl(idx, j, 64);
            const float2* srow = (const float2*)(src + (size_t)nb * DIM);
            float2 v = srow[l32];
            if (half == 0) { ax += v.x; ay += v.y; }
        }
    }
    // merge the two half-wave partial sums
    ax += __shfl_xor(ax, 32, 64);
    ay += __shfl_xor(ay, 32, 64);
    float ss = ax * ax + ay * ay;
    #pragma unroll
    for (int o = 16; o > 0; o >>= 1) ss += __shfl_xor(ss, o, 64);
    float inv = 1.0f / fmaxf(sqrtf(ss), 1e-12f);
    float2 n2 = make_float2(ax * inv, ay * inv);
    if (half == 0) {
        if (write_emb) ((float2*)(demb + (size_t)row * DIM))[l32] = n2;
        float2* ds = (float2*)(dsum + (size_t)row * DIM);
        float2 old = init_sum ? ((const float2*)(own + (size_t)row * DIM))[l32] : ds[l32];
        ds[l32] = make_float2(old.x + n2.x, old.y + n2.y);
    }
}

// ---------------- launch ----------------

extern "C" void kernel_launch(void* const* d_in, const int* in_sizes, int n_in,
                              void* d_out, int out_size, void* d_ws, size_t ws_size,
                              hipStream_t stream) {
    const float* user_table = (const float*)d_in[0];
    const float* item_table = (const float*)d_in[1];
    const int*   u_idx      = (const int*)d_in[2];
    const int*   i_idx      = (const int*)d_in[3];
    const int*   edges      = (const int*)d_in[4];
    const int*   u_nodes    = edges;              // edge_index[0]
    const int*   i_nodes    = edges + NUM_EDGES;  // edge_index[1]
    float*       out        = (float*)d_out;

    // ---- workspace layout (f32, same footprint as rounds 6-7) ----
    float* usum = (float*)d_ws;
    float* uA   = usum + NU64;
    float* uB   = uA + NU64;
    float* isum = uB + NU64;
    float* iA   = isum + NI64;
    float* iB   = iA + NI64;

    int* ip     = (int*)(iB + NI64);
    int* u_offs = ip;                      // NUM_USERS + 1
    int* i_offs = u_offs + NUM_USERS + 1;  // NUM_ITEMS + 1
    int* u_cnt  = i_offs + NUM_ITEMS + 1;  // NUM_USERS
    int* i_cnt  = u_cnt + NUM_USERS;       // NUM_ITEMS
    int* u_adj  = i_cnt + NUM_ITEMS;       // NUM_EDGES
    int* i_adj  = u_adj + NUM_EDGES;       // NUM_EDGES
    int* bsum   = i_adj + NUM_EDGES;       // 256
    int* gcurU  = bsum + 256;              // NBU
    int* gcurI  = gcurU + NBU;             // NBI

    // staging reuses the idle uB/iB ping-pong buffers:
    // NBU*CAPU*8B = 19.3 MB <= uB (51.2 MB); NBI*CAPI*8B = 19.3 MB <= iB (25.6 MB).
    // Consumed by bucket_place before layer 1 writes uB/iB.
    int2* stageU = (int2*)uB;
    int2* stageI = (int2*)iB;

    // ---- CSR build (hist fused into bucket_scatter) ----
    hipMemsetAsync(u_cnt, 0, (size_t)(NUM_USERS + NUM_ITEMS) * sizeof(int), stream);
    hipMemsetAsync(gcurU, 0, (NBU + NBI) * sizeof(int), stream);

    int nblkA = (NUM_EDGES + 2047) / 2048;
    bucket_scatter<<<nblkA, 256, 0, stream>>>(u_nodes, i_nodes, u_cnt, i_cnt,
                                              gcurU, gcurI, stageU, stageI);

    int nb_u = (NUM_USERS + 1023) / 1024;
    int nb_i = (NUM_ITEMS + 1023) / 1024;
    scan_pass1<<<nb_u, 256, 0, stream>>>(u_cnt, bsum, NUM_USERS);
    scan_small_excl<<<1, 256, 0, stream>>>(bsum, nb_u);
    scan_pass3<<<nb_u, 256, 0, stream>>>(u_cnt, bsum, u_offs, NUM_USERS);
    scan_pass1<<<nb_i, 256, 0, stream>>>(i_cnt, bsum, NUM_ITEMS);
    scan_small_excl<<<1, 256, 0, stream>>>(bsum, nb_i);
    scan_pass3<<<nb_i, 256, 0, stream>>>(i_cnt, bsum, i_offs, NUM_ITEMS);
    tail_kernel<<<1, 64, 0, stream>>>(u_offs, i_offs);

    bucket_place<<<NBU + NBI, 1024, 0, stream>>>(u_offs, i_offs, gcurU, gcurI,
                                                 stageU, stageI, u_adj, i_adj);

    // ---- 3 fused pull layers (layer 0 seeds the running sums from the tables) ----
    const float* uprev = user_table;
    const float* iprev = item_table;
    float* ucur = uA; float* icur = iA;
    float* ualt = uB; float* ialt = iB;
    long long waves = (long long)(NUM_USERS + NUM_ITEMS);
    int blocks = (int)((waves * 64 + 255) / 256);
    for (int l = 0; l < NUM_LAYERS; ++l) {
        int write_emb = (l < NUM_LAYERS - 1) ? 1 : 0;
        int init_sum  = (l == 0) ? 1 : 0;
        pull_norm_kernel<<<blocks, 256, 0, stream>>>(u_offs, u_adj, i_offs, i_adj,
                                                     uprev, iprev, ucur, icur, usum, isum,
                                                     user_table, item_table,
                                                     write_emb, init_sum);
        uprev = ucur; iprev = icur;
        float* t;
        t = ucur; ucur = ualt; ualt = t;
        t = icur; icur = ialt; ialt = t;
    }

    {
        long long tb = (long long)BATCH * 64;
        final_dot_kernel<<<(int)((tb + 255) / 256), 256, 0, stream>>>(usum, isum, u_idx, i_idx, out);
    }
}

// Round 12
// 694.841 us; speedup vs baseline: 3.8309x; 1.1075x over previous
//
#include <hip/hip_runtime.h>
#include <hip/hip_fp16.h>

#define NUM_USERS 200000
#define NUM_ITEMS 100000
#define DIM 64
#define NUM_EDGES 2000000
#define BATCH 16384
#define NUM_LAYERS 3

#define NU64 ((size_t)NUM_USERS * DIM)
#define NI64 ((size_t)NUM_ITEMS * DIM)

// bucketed CSR fill: user buckets = 2048-node ranges, item buckets = 1024-node ranges
#define RU_SHIFT 11
#define RI_SHIFT 10
#define NBU 98   // ceil(200000 / 2048)
#define NBI 98   // ceil(100000 / 1024)
#define CAPU 24576  // fixed staging capacity per bucket (expected ~20480, 28-sigma margin)
#define CAPI 24576

// ---------------- init (fp16 table copies) + final dot ----------------

__global__ void convert_kernel(const float4* __restrict__ ut, const float4* __restrict__ it,
                               uint2* __restrict__ uH, uint2* __restrict__ iH) {
    int idx = blockIdx.x * blockDim.x + threadIdx.x;
    const int n4u = (int)(NU64 / 4), n4i = (int)(NI64 / 4);
    if (idx < n4u) {
        float4 v = ut[idx];
        __half2 h0 = __floats2half2_rn(v.x, v.y);
        __half2 h1 = __floats2half2_rn(v.z, v.w);
        uint2 p; p.x = *(unsigned*)&h0; p.y = *(unsigned*)&h1;
        uH[idx] = p;
    } else if (idx < n4u + n4i) {
        int k = idx - n4u;
        float4 v = it[k];
        __half2 h0 = __floats2half2_rn(v.x, v.y);
        __half2 h1 = __floats2half2_rn(v.z, v.w);
        uint2 p; p.x = *(unsigned*)&h0; p.y = *(unsigned*)&h1;
        iH[k] = p;
    }
}

__global__ void final_dot_kernel(const float* __restrict__ user_sum, const float* __restrict__ item_sum,
                                 const int* __restrict__ u_idx, const int* __restrict__ i_idx,
                                 float* __restrict__ out) {
    int b    = (blockIdx.x * blockDim.x + threadIdx.x) >> 6;
    int lane = threadIdx.x & 63;
    if (b >= BATCH) return;
    int u = u_idx[b];
    int i = i_idx[b];
    float p = user_sum[(size_t)u * DIM + lane] * item_sum[(size_t)i * DIM + lane];
    #pragma unroll
    for (int o = 32; o > 0; o >>= 1) p += __shfl_xor(p, o, 64);
    if (lane == 0) out[b] = p * (1.0f / ((NUM_LAYERS + 1) * (NUM_LAYERS + 1)));
}

// ---------------- CSR construction (identical to round-10 proven path) ----------------

__global__ void scan_pass1(const int* __restrict__ cnt, int* __restrict__ bsum, int n) {
    __shared__ int s[256];
    int b = blockIdx.x, t = threadIdx.x;
    int base = b * 1024 + t * 4;
    int v = 0;
    #pragma unroll
    for (int k = 0; k < 4; ++k) if (base + k < n) v += cnt[base + k];
    s[t] = v;
    __syncthreads();
    for (int off = 128; off > 0; off >>= 1) {
        if (t < off) s[t] += s[t + off];
        __syncthreads();
    }
    if (t == 0) bsum[b] = s[0];
}

__global__ void scan_small_excl(int* __restrict__ data, int n) {
    __shared__ int s[256];
    int t = threadIdx.x;
    int v0 = (t < n) ? data[t] : 0;
    s[t] = v0;
    __syncthreads();
    for (int off = 1; off < 256; off <<= 1) {
        int v = (t >= off) ? s[t - off] : 0;
        __syncthreads();
        s[t] += v;
        __syncthreads();
    }
    if (t < n) data[t] = s[t] - v0;
}

__global__ void scan_pass3(const int* __restrict__ cnt, const int* __restrict__ bsum,
                           int* __restrict__ offs, int n) {
    __shared__ int s[256];
    int b = blockIdx.x, t = threadIdx.x;
    int base = b * 1024 + t * 4;
    int v[4];
    int tl = 0;
    #pragma unroll
    for (int k = 0; k < 4; ++k) {
        v[k] = (base + k < n) ? cnt[base + k] : 0;
        tl += v[k];
    }
    s[t] = tl;
    __syncthreads();
    for (int off = 1; off < 256; off <<= 1) {
        int x = (t >= off) ? s[t - off] : 0;
        __syncthreads();
        s[t] += x;
        __syncthreads();
    }
    int run = bsum[b] + s[t] - tl;
    #pragma unroll
    for (int k = 0; k < 4; ++k) {
        if (base + k < n) { offs[base + k] = run; run += v[k]; }
    }
}

__global__ void tail_kernel(int* __restrict__ u_offs, int* __restrict__ i_offs) {
    if (threadIdx.x == 0) { u_offs[NUM_USERS] = NUM_EDGES; i_offs[NUM_ITEMS] = NUM_EDGES; }
}

// Pass A: LDS-binned bucket scatter into FIXED-capacity per-bucket staging,
// with the per-node histogram fused in.
__global__ void bucket_scatter(const int* __restrict__ un, const int* __restrict__ in_,
                               int* __restrict__ u_cnt, int* __restrict__ i_cnt,
                               int* __restrict__ gcurU, int* __restrict__ gcurI,
                               int2* __restrict__ stageU, int2* __restrict__ stageI) {
    __shared__ int cntU[NBU], cntI[NBI];
    __shared__ int baseU[NBU], baseI[NBI];
    int t = threadIdx.x;
    if (t < NBU) cntU[t] = 0;
    if (t < NBI) cntI[t] = 0;
    __syncthreads();
    int e0 = blockIdx.x * 2048 + t;
    int u[8], it[8], bu[8], bi[8], ru[8], ri[8];
    bool valid[8];
    #pragma unroll
    for (int k = 0; k < 8; ++k) {
        int e = e0 + k * 256;
        valid[k] = (e < NUM_EDGES);
        if (valid[k]) {
            u[k]  = un[e];
            it[k] = in_[e];
            atomicAdd(&u_cnt[u[k]], 1);   // fused per-node histogram
            atomicAdd(&i_cnt[it[k]], 1);
            bu[k] = u[k]  >> RU_SHIFT;
            bi[k] = it[k] >> RI_SHIFT;
            ru[k] = atomicAdd(&cntU[bu[k]], 1);
            ri[k] = atomicAdd(&cntI[bi[k]], 1);
        }
    }
    __syncthreads();
    if (t < NBU) baseU[t] = t * CAPU + atomicAdd(&gcurU[t], cntU[t]);
    if (t < NBI) baseI[t] = t * CAPI + atomicAdd(&gcurI[t], cntI[t]);
    __syncthreads();
    #pragma unroll
    for (int k = 0; k < 8; ++k) {
        if (valid[k]) {
            stageU[baseU[bu[k]] + ru[k]] = make_int2(u[k], it[k]);
            stageI[baseI[bi[k]] + ri[k]] = make_int2(it[k], u[k]);
        }
    }
}

// Pass B: one block per bucket; LDS cursors place records (L2-local, no global atomics).
__global__ void bucket_place(const int* __restrict__ u_offs, const int* __restrict__ i_offs,
                             const int* __restrict__ gcurU, const int* __restrict__ gcurI,
                             const int2* __restrict__ stageU, const int2* __restrict__ stageI,
                             int* __restrict__ u_adj, int* __restrict__ i_adj) {
    __shared__ int offs_l[2049];
    __shared__ int cur[2048];
    int b = blockIdx.x, t = threadIdx.x;
    const int* offs; const int2* stage; int* adj; int lo, range, nrec;
    if (b < NBU) {
        offs = u_offs; adj = u_adj;
        stage = stageU + (size_t)b * CAPU;
        nrec  = gcurU[b];
        lo = b << RU_SHIFT;
        range = NUM_USERS - lo; if (range > 2048) range = 2048;
    } else {
        int bb = b - NBU;
        offs = i_offs; adj = i_adj;
        stage = stageI + (size_t)bb * CAPI;
        nrec  = gcurI[bb];
        lo = bb << RI_SHIFT;
        range = NUM_ITEMS - lo; if (range > 1024) range = 1024;
    }
    for (int k = t; k < range + 1; k += blockDim.x) offs_l[k] = offs[lo + k];
    for (int k = t; k < range; k += blockDim.x) cur[k] = 0;
    __syncthreads();
    for (int r = t; r < nrec; r += blockDim.x) {
        int2 rec = stage[r];
        int loc = rec.x - lo;
        int p = atomicAdd(&cur[loc], 1);
        adj[offs_l[loc] + p] = rec.y;
    }
}

// ---------------- fused pull + normalize + sum (proven float2 structure, fp16 payload) ----------------
// One wave per row; lanes 0-31 process neighbor j, lanes 32-63 neighbor j+1,
// each lane loads __half2 (4B) = 2 dims. Accumulate/normalize f32; emb stored fp16,
// running sum f32. Layer 0 seeds the running sum from the original f32 table.
__global__ void pull_norm_kernel(const int* __restrict__ u_offs, const int* __restrict__ u_adj,
                                 const int* __restrict__ i_offs, const int* __restrict__ i_adj,
                                 const __half* __restrict__ uprev, const __half* __restrict__ iprev,
                                 __half* __restrict__ unew, __half* __restrict__ inew,
                                 float* __restrict__ usum, float* __restrict__ isum,
                                 const float* __restrict__ uown, const float* __restrict__ iown,
                                 int write_emb, int init_sum) {
    int w    = (blockIdx.x * blockDim.x + threadIdx.x) >> 6;
    int lane = threadIdx.x & 63;
    int half = lane >> 5;   // 0 or 1
    int l32  = lane & 31;
    const int* offs; const int* adj; const __half* src; __half* demb; float* dsum; const float* own; int row;
    if (w < NUM_USERS) {
        row = w; offs = u_offs; adj = u_adj; src = iprev; demb = unew; dsum = usum; own = uown;
    } else {
        row = w - NUM_USERS;
        if (row >= NUM_ITEMS) return;
        offs = i_offs; adj = i_adj; src = uprev; demb = inew; dsum = isum; own = iown;
    }
    int start = offs[row], end = offs[row + 1];
    int cnt = end - start;
    float ax = 0.0f, ay = 0.0f;
    for (int base = 0; base < cnt; base += 64) {
        int rem = cnt - base;
        if (rem > 64) rem = 64;
        int idx = (lane < rem) ? adj[start + base + lane] : 0;
        int j = 0;
        // 4 pairs (8 neighbors) per unrolled iteration
        for (; j + 8 <= rem; j += 8) {
            #pragma unroll
            for (int p = 0; p < 4; ++p) {
                int nb = __shfl(idx, j + 2 * p + half, 64);
                const __half2* srow = (const __half2*)(src + (size_t)nb * DIM);
                float2 v = __half22float2(srow[l32]);
                ax += v.x; ay += v.y;
            }
        }
        for (; j + 2 <= rem; j += 2) {
            int nb = __shfl(idx, j + half, 64);
            const __half2* srow = (const __half2*)(src + (size_t)nb * DIM);
            float2 v = __half22float2(srow[l32]);
            ax += v.x; ay += v.y;
        }
        if (j < rem) {  // odd leftover neighbor: lanes 0-31 only
            int nb = __shfl(idx, j, 64);
            const __half2* srow = (const __half2*)(src + (size_t)nb * DIM);
            float2 v = __half22float2(srow[l32]);
            if (half == 0) { ax += v.x; ay += v.y; }
        }
    }
    // merge the two half-wave partial sums
    ax += __shfl_xor(ax, 32, 64);
    ay += __shfl_xor(ay, 32, 64);
    float ss = ax * ax + ay * ay;
    #pragma unroll
    for (int o = 16; o > 0; o >>= 1) ss += __shfl_xor(ss, o, 64);
    float inv = 1.0f / fmaxf(sqrtf(ss), 1e-12f);
    float nx = ax * inv, ny = ay * inv;
    if (half == 0) {
        if (write_emb) ((__half2*)(demb + (size_t)row * DIM))[l32] = __floats2half2_rn(nx, ny);
        float2* ds = (float2*)(dsum + (size_t)row * DIM);
        float2 old = init_sum ? ((const float2*)(own + (size_t)row * DIM))[l32] : ds[l32];
        ds[l32] = make_float2(old.x + nx, old.y + ny);
    }
}

// ---------------- launch ----------------

extern "C" void kernel_launch(void* const* d_in, const int* in_sizes, int n_in,
                              void* d_out, int out_size, void* d_ws, size_t ws_size,
                              hipStream_t stream) {
    const float* user_table = (const float*)d_in[0];
    const float* item_table = (const float*)d_in[1];
    const int*   u_idx      = (const int*)d_in[2];
    const int*   i_idx      = (const int*)d_in[3];
    const int*   edges      = (const int*)d_in[4];
    const int*   u_nodes    = edges;              // edge_index[0]
    const int*   i_nodes    = edges + NUM_EDGES;  // edge_index[1]
    float*       out        = (float*)d_out;

    // ---- workspace layout (~211 MB) ----
    float*  usum = (float*)d_ws;            // NU64 f32 (51.2 MB)
    float*  isum = usum + NU64;             // NI64 f32 (25.6 MB)
    __half* uH0  = (__half*)(isum + NI64);  // NU64 fp16 (25.6 MB)
    __half* uH1  = uH0 + NU64;              // NU64 fp16
    __half* iH0  = (__half*)(uH1 + NU64);   // NI64 fp16 (12.8 MB)
    __half* iH1  = iH0 + NI64;              // NI64 fp16

    int* ip     = (int*)(iH1 + NI64);
    int* u_offs = ip;                      // NUM_USERS + 1
    int* i_offs = u_offs + NUM_USERS + 1;  // NUM_ITEMS + 1
    int* u_cnt  = i_offs + NUM_ITEMS + 1;  // NUM_USERS
    int* i_cnt  = u_cnt + NUM_USERS;       // NUM_ITEMS
    int* u_adj  = i_cnt + NUM_ITEMS;       // NUM_EDGES
    int* i_adj  = u_adj + NUM_EDGES;       // NUM_EDGES
    int* bsum   = i_adj + NUM_EDGES;       // 256
    int* gcurU  = bsum + 256;              // NBU
    int* gcurI  = gcurU + NBU;             // NBI
    int2* stageU = (int2*)(gcurI + NBI);   // NBU*CAPU int2 (19.3 MB)
    int2* stageI = stageU + (size_t)NBU * CAPU;  // NBI*CAPI int2 (19.3 MB)

    // ---- init: fp16 copies of the tables (running sums seeded in pull layer 0) ----
    {
        int n4 = (int)((NU64 + NI64) / 4);
        convert_kernel<<<(n4 + 255) / 256, 256, 0, stream>>>(
            (const float4*)user_table, (const float4*)item_table,
            (uint2*)uH0, (uint2*)iH0);
    }

    // ---- CSR build (hist fused into bucket_scatter) ----
    hipMemsetAsync(u_cnt, 0, (size_t)(NUM_USERS + NUM_ITEMS) * sizeof(int), stream);
    hipMemsetAsync(gcurU, 0, (NBU + NBI) * sizeof(int), stream);

    int nblkA = (NUM_EDGES + 2047) / 2048;
    bucket_scatter<<<nblkA, 256, 0, stream>>>(u_nodes, i_nodes, u_cnt, i_cnt,
                                              gcurU, gcurI, stageU, stageI);

    int nb_u = (NUM_USERS + 1023) / 1024;
    int nb_i = (NUM_ITEMS + 1023) / 1024;
    scan_pass1<<<nb_u, 256, 0, stream>>>(u_cnt, bsum, NUM_USERS);
    scan_small_excl<<<1, 256, 0, stream>>>(bsum, nb_u);
    scan_pass3<<<nb_u, 256, 0, stream>>>(u_cnt, bsum, u_offs, NUM_USERS);
    scan_pass1<<<nb_i, 256, 0, stream>>>(i_cnt, bsum, NUM_ITEMS);
    scan_small_excl<<<1, 256, 0, stream>>>(bsum, nb_i);
    scan_pass3<<<nb_i, 256, 0, stream>>>(i_cnt, bsum, i_offs, NUM_ITEMS);
    tail_kernel<<<1, 64, 0, stream>>>(u_offs, i_offs);

    bucket_place<<<NBU + NBI, 1024, 0, stream>>>(u_offs, i_offs, gcurU, gcurI,
                                                 stageU, stageI, u_adj, i_adj);

    // ---- 3 fused pull layers (fp16 gathers; layer 0 seeds sums from f32 tables) ----
    const __half* uprev = uH0;
    const __half* iprev = iH0;
    __half* ucur = uH1; __half* icur = iH1;
    __half* ualt = uH0; __half* ialt = iH0;
    long long waves = (long long)(NUM_USERS + NUM_ITEMS);
    int blocks = (int)((waves * 64 + 255) / 256);
    for (int l = 0; l < NUM_LAYERS; ++l) {
        int write_emb = (l < NUM_LAYERS - 1) ? 1 : 0;
        int init_sum  = (l == 0) ? 1 : 0;
        pull_norm_kernel<<<blocks, 256, 0, stream>>>(u_offs, u_adj, i_offs, i_adj,
                                                     uprev, iprev, ucur, icur, usum, isum,
                                                     user_table, item_table,
                                                     write_emb, init_sum);
        uprev = ucur; iprev = icur;
        __half* t;
        t = ucur; ucur = ualt; ualt = t;
        t = icur; icur = ialt; ialt = t;
    }

    {
        long long tb = (long long)BATCH * 64;
        final_dot_kernel<<<(int)((tb + 255) / 256), 256, 0, stream>>>(usum, isum, u_idx, i_idx, out);
    }
}

// Round 13
// 583.001 us; speedup vs baseline: 4.5658x; 1.1918x over previous
//
#include <hip/hip_runtime.h>
#include <hip/hip_fp16.h>

#define NUM_USERS 200000
#define NUM_ITEMS 100000
#define DIM 64
#define NUM_EDGES 2000000
#define BATCH 16384
#define NUM_LAYERS 3

#define NU64 ((size_t)NUM_USERS * DIM)
#define NI64 ((size_t)NUM_ITEMS * DIM)

// bucketed CSR: user buckets = 2048-node ranges, item buckets = 1024-node ranges
#define RU_SHIFT 11
#define RI_SHIFT 10
#define NBU 98   // ceil(200000 / 2048)
#define NBI 98   // ceil(100000 / 1024)
#define CAPU 24576  // fixed capacity per bucket (expected ~20480, 28-sigma margin)
#define CAPI 24576
#define EPB 1024    // edges per scatter block

// ---------------- init (fp16 table copies) + final dot ----------------

__global__ void convert_kernel(const float4* __restrict__ ut, const float4* __restrict__ it,
                               uint2* __restrict__ uH, uint2* __restrict__ iH) {
    int idx = blockIdx.x * blockDim.x + threadIdx.x;
    const int n4u = (int)(NU64 / 4), n4i = (int)(NI64 / 4);
    if (idx < n4u) {
        float4 v = ut[idx];
        __half2 h0 = __floats2half2_rn(v.x, v.y);
        __half2 h1 = __floats2half2_rn(v.z, v.w);
        uint2 p; p.x = *(unsigned*)&h0; p.y = *(unsigned*)&h1;
        uH[idx] = p;
    } else if (idx < n4u + n4i) {
        int k = idx - n4u;
        float4 v = it[k];
        __half2 h0 = __floats2half2_rn(v.x, v.y);
        __half2 h1 = __floats2half2_rn(v.z, v.w);
        uint2 p; p.x = *(unsigned*)&h0; p.y = *(unsigned*)&h1;
        iH[k] = p;
    }
}

__global__ void final_dot_kernel(const float* __restrict__ user_sum, const float* __restrict__ item_sum,
                                 const int* __restrict__ u_idx, const int* __restrict__ i_idx,
                                 float* __restrict__ out) {
    int b    = (blockIdx.x * blockDim.x + threadIdx.x) >> 6;
    int lane = threadIdx.x & 63;
    if (b >= BATCH) return;
    int u = u_idx[b];
    int i = i_idx[b];
    float p = user_sum[(size_t)u * DIM + lane] * item_sum[(size_t)i * DIM + lane];
    #pragma unroll
    for (int o = 32; o > 0; o >>= 1) p += __shfl_xor(p, o, 64);
    if (lane == 0) out[b] = p * (1.0f / ((NUM_LAYERS + 1) * (NUM_LAYERS + 1)));
}

// ---------------- CSR construction v2 (no global hist, no global scan) ----------------

// Pass A: per-wave-replicated LDS binning, fixed-capacity per-bucket staging.
__global__ void bucket_scatter(const int* __restrict__ un, const int* __restrict__ in_,
                               int* __restrict__ gcurU, int* __restrict__ gcurI,
                               int2* __restrict__ stageU, int2* __restrict__ stageI) {
    __shared__ int cntU[4][NBU], cntI[4][NBI];
    __shared__ int baseU[4][NBU], baseI[4][NBI];
    int t = threadIdx.x;
    int w = t >> 6;  // wave 0..3
    for (int k = t; k < 4 * NBU; k += 256) ((int*)cntU)[k] = 0;
    for (int k = t; k < 4 * NBI; k += 256) ((int*)cntI)[k] = 0;
    __syncthreads();
    int e0 = blockIdx.x * EPB + t;
    int u[4], it[4], bu[4], bi[4], ru[4], ri[4];
    bool valid[4];
    #pragma unroll
    for (int k = 0; k < 4; ++k) {
        int e = e0 + k * 256;
        valid[k] = (e < NUM_EDGES);
        if (valid[k]) {
            u[k]  = un[e];
            it[k] = in_[e];
            bu[k] = u[k]  >> RU_SHIFT;
            bi[k] = it[k] >> RI_SHIFT;
            ru[k] = atomicAdd(&cntU[w][bu[k]], 1);
            ri[k] = atomicAdd(&cntI[w][bi[k]], 1);
        }
    }
    __syncthreads();
    if (t < NBU) {
        int c0 = cntU[0][t], c1 = cntU[1][t], c2 = cntU[2][t], c3 = cntU[3][t];
        int b = t * CAPU + atomicAdd(&gcurU[t], c0 + c1 + c2 + c3);
        baseU[0][t] = b; baseU[1][t] = b + c0; baseU[2][t] = b + c0 + c1; baseU[3][t] = b + c0 + c1 + c2;
    }
    if (t < NBI) {
        int c0 = cntI[0][t], c1 = cntI[1][t], c2 = cntI[2][t], c3 = cntI[3][t];
        int b = t * CAPI + atomicAdd(&gcurI[t], c0 + c1 + c2 + c3);
        baseI[0][t] = b; baseI[1][t] = b + c0; baseI[2][t] = b + c0 + c1; baseI[3][t] = b + c0 + c1 + c2;
    }
    __syncthreads();
    #pragma unroll
    for (int k = 0; k < 4; ++k) {
        if (valid[k]) {
            stageU[baseU[w][bu[k]] + ru[k]] = make_int2(u[k], it[k]);
            stageI[baseI[w][bi[k]] + ri[k]] = make_int2(it[k], u[k]);
        }
    }
}

// Pass B: one block per bucket. Per-node counts + LDS prefix scan produce
// offs/deg locally (adjacency has fixed per-bucket capacity), then place
// records with LDS cursors. No global scan chain needed.
__global__ void bucket_place(const int* __restrict__ gcurU, const int* __restrict__ gcurI,
                             const int2* __restrict__ stageU, const int2* __restrict__ stageI,
                             int* __restrict__ u_offs, int* __restrict__ i_offs,
                             int* __restrict__ u_deg, int* __restrict__ i_deg,
                             int* __restrict__ u_adj, int* __restrict__ i_adj) {
    __shared__ int cnt[2048];
    __shared__ int offs_l[2048];
    __shared__ int wsum[1024];
    int b = blockIdx.x, t = threadIdx.x;
    const int2* stage; int* adj; int* offs; int* deg; int lo, range, nrec, bbase;
    if (b < NBU) {
        stage = stageU + (size_t)b * CAPU; adj = u_adj; offs = u_offs; deg = u_deg;
        nrec = gcurU[b]; lo = b << RU_SHIFT; bbase = b * CAPU;
        range = NUM_USERS - lo; if (range > 2048) range = 2048;
    } else {
        int bb = b - NBU;
        stage = stageI + (size_t)bb * CAPI; adj = i_adj; offs = i_offs; deg = i_deg;
        nrec = gcurI[bb]; lo = bb << RI_SHIFT; bbase = bb * CAPI;
        range = NUM_ITEMS - lo; if (range > 1024) range = 1024;
    }
    cnt[t] = 0; cnt[t + 1024] = 0;
    __syncthreads();
    for (int r = t; r < nrec; r += 1024) atomicAdd(&cnt[stage[r].x - lo], 1);
    __syncthreads();
    int c0 = cnt[2 * t], c1 = cnt[2 * t + 1];
    int s = c0 + c1;
    wsum[t] = s;
    __syncthreads();
    for (int off = 1; off < 1024; off <<= 1) {
        int v = (t >= off) ? wsum[t - off] : 0;
        __syncthreads();
        wsum[t] += v;
        __syncthreads();
    }
    int excl = wsum[t] - s;  // exclusive prefix of node 2t
    offs_l[2 * t] = excl;
    offs_l[2 * t + 1] = excl + c0;
    if (2 * t < range)     { offs[lo + 2 * t]     = bbase + excl;      deg[lo + 2 * t]     = c0; }
    if (2 * t + 1 < range) { offs[lo + 2 * t + 1] = bbase + excl + c0; deg[lo + 2 * t + 1] = c1; }
    cnt[2 * t] = 0; cnt[2 * t + 1] = 0;   // reuse as placement cursors
    __syncthreads();
    for (int r = t; r < nrec; r += 1024) {
        int2 rec = stage[r];
        int loc = rec.x - lo;
        int p = atomicAdd(&cnt[loc], 1);
        adj[bbase + offs_l[loc] + p] = rec.y;
    }
}

// ---------------- fused pull + normalize + sum (proven float2 structure, fp16 payload) ----------------
// One wave per row; lanes 0-31 process neighbor j, lanes 32-63 neighbor j+1,
// each lane loads __half2 (4B) = 2 dims. Accumulate/normalize f32; emb stored fp16,
// running sum f32. Layer 0 seeds the running sum from the original f32 table.
__global__ void pull_norm_kernel(const int* __restrict__ u_offs, const int* __restrict__ u_deg,
                                 const int* __restrict__ u_adj,
                                 const int* __restrict__ i_offs, const int* __restrict__ i_deg,
                                 const int* __restrict__ i_adj,
                                 const __half* __restrict__ uprev, const __half* __restrict__ iprev,
                                 __half* __restrict__ unew, __half* __restrict__ inew,
                                 float* __restrict__ usum, float* __restrict__ isum,
                                 const float* __restrict__ uown, const float* __restrict__ iown,
                                 int write_emb, int init_sum) {
    int w    = (blockIdx.x * blockDim.x + threadIdx.x) >> 6;
    int lane = threadIdx.x & 63;
    int half = lane >> 5;   // 0 or 1
    int l32  = lane & 31;
    const int* offs; const int* deg; const int* adj; const __half* src; __half* demb;
    float* dsum; const float* own; int row;
    if (w < NUM_USERS) {
        row = w; offs = u_offs; deg = u_deg; adj = u_adj; src = iprev; demb = unew; dsum = usum; own = uown;
    } else {
        row = w - NUM_USERS;
        if (row >= NUM_ITEMS) return;
        offs = i_offs; deg = i_deg; adj = i_adj; src = uprev; demb = inew; dsum = isum; own = iown;
    }
    int start = offs[row];
    int cnt   = deg[row];
    float ax = 0.0f, ay = 0.0f;
    for (int base = 0; base < cnt; base += 64) {
        int rem = cnt - base;
        if (rem > 64) rem = 64;
        int idx = (lane < rem) ? adj[start + base + lane] : 0;
        int j = 0;
        // 4 pairs (8 neighbors) per unrolled iteration
        for (; j + 8 <= rem; j += 8) {
            #pragma unroll
            for (int p = 0; p < 4; ++p) {
                int nb = __shfl(idx, j + 2 * p + half, 64);
                const __half2* srow = (const __half2*)(src + (size_t)nb * DIM);
                float2 v = __half22float2(srow[l32]);
                ax += v.x; ay += v.y;
            }
        }
        for (; j + 2 <= rem; j += 2) {
            int nb = __shfl(idx, j + half, 64);
            const __half2* srow = (const __half2*)(src + (size_t)nb * DIM);
            float2 v = __half22float2(srow[l32]);
            ax += v.x; ay += v.y;
        }
        if (j < rem) {  // odd leftover neighbor: lanes 0-31 only
            int nb = __shfl(idx, j, 64);
            const __half2* srow = (const __half2*)(src + (size_t)nb * DIM);
            float2 v = __half22float2(srow[l32]);
            if (half == 0) { ax += v.x; ay += v.y; }
        }
    }
    // merge the two half-wave partial sums
    ax += __shfl_xor(ax, 32, 64);
    ay += __shfl_xor(ay, 32, 64);
    float ss = ax * ax + ay * ay;
    #pragma unroll
    for (int o = 16; o > 0; o >>= 1) ss += __shfl_xor(ss, o, 64);
    float inv = 1.0f / fmaxf(sqrtf(ss), 1e-12f);
    float nx = ax * inv, ny = ay * inv;
    if (half == 0) {
        if (write_emb) ((__half2*)(demb + (size_t)row * DIM))[l32] = __floats2half2_rn(nx, ny);
        float2* ds = (float2*)(dsum + (size_t)row * DIM);
        float2 old = init_sum ? ((const float2*)(own + (size_t)row * DIM))[l32] : ds[l32];
        ds[l32] = make_float2(old.x + nx, old.y + ny);
    }
}

// ---------------- launch ----------------

extern "C" void kernel_launch(void* const* d_in, const int* in_sizes, int n_in,
                              void* d_out, int out_size, void* d_ws, size_t ws_size,
                              hipStream_t stream) {
    const float* user_table = (const float*)d_in[0];
    const float* item_table = (const float*)d_in[1];
    const int*   u_idx      = (const int*)d_in[2];
    const int*   i_idx      = (const int*)d_in[3];
    const int*   edges      = (const int*)d_in[4];
    const int*   u_nodes    = edges;              // edge_index[0]
    const int*   i_nodes    = edges + NUM_EDGES;  // edge_index[1]
    float*       out        = (float*)d_out;

    // ---- workspace layout (~215 MB) ----
    float*  usum = (float*)d_ws;            // NU64 f32 (51.2 MB)
    float*  isum = usum + NU64;             // NI64 f32 (25.6 MB)
    __half* uH0  = (__half*)(isum + NI64);  // NU64 fp16 (25.6 MB)
    __half* uH1  = uH0 + NU64;              // NU64 fp16
    __half* iH0  = (__half*)(uH1 + NU64);   // NI64 fp16 (12.8 MB)
    __half* iH1  = iH0 + NI64;              // NI64 fp16

    int* ip     = (int*)(iH1 + NI64);
    int* u_offs = ip;                        // NUM_USERS
    int* i_offs = u_offs + NUM_USERS;        // NUM_ITEMS
    int* u_deg  = i_offs + NUM_ITEMS;        // NUM_USERS
    int* i_deg  = u_deg + NUM_USERS;         // NUM_ITEMS
    int* u_adj  = i_deg + NUM_ITEMS;         // NBU*CAPU (9.6 MB)
    int* i_adj  = u_adj + (size_t)NBU * CAPU;  // NBI*CAPI (9.6 MB)
    int* gcurU  = i_adj + (size_t)NBI * CAPI;  // NBU
    int* gcurI  = gcurU + NBU;               // NBI
    int2* stageU = (int2*)(gcurI + NBI);     // NBU*CAPU int2 (19.3 MB)
    int2* stageI = stageU + (size_t)NBU * CAPU;  // NBI*CAPI int2 (19.3 MB)

    // ---- init: fp16 copies of the tables (running sums seeded in pull layer 0) ----
    {
        int n4 = (int)((NU64 + NI64) / 4);
        convert_kernel<<<(n4 + 255) / 256, 256, 0, stream>>>(
            (const float4*)user_table, (const float4*)item_table,
            (uint2*)uH0, (uint2*)iH0);
    }

    // ---- CSR build v2 ----
    hipMemsetAsync(gcurU, 0, (NBU + NBI) * sizeof(int), stream);

    int nblkA = (NUM_EDGES + EPB - 1) / EPB;
    bucket_scatter<<<nblkA, 256, 0, stream>>>(u_nodes, i_nodes, gcurU, gcurI, stageU, stageI);
    bucket_place<<<NBU + NBI, 1024, 0, stream>>>(gcurU, gcurI, stageU, stageI,
                                                 u_offs, i_offs, u_deg, i_deg, u_adj, i_adj);

    // ---- 3 fused pull layers (fp16 gathers; layer 0 seeds sums from f32 tables) ----
    const __half* uprev = uH0;
    const __half* iprev = iH0;
    __half* ucur = uH1; __half* icur = iH1;
    __half* ualt = uH0; __half* ialt = iH0;
    long long waves = (long long)(NUM_USERS + NUM_ITEMS);
    int blocks = (int)((waves * 64 + 255) / 256);
    for (int l = 0; l < NUM_LAYERS; ++l) {
        int write_emb = (l < NUM_LAYERS - 1) ? 1 : 0;
        int init_sum  = (l == 0) ? 1 : 0;
        pull_norm_kernel<<<blocks, 256, 0, stream>>>(u_offs, u_deg, u_adj,
                                                     i_offs, i_deg, i_adj,
                                                     uprev, iprev, ucur, icur, usum, isum,
                                                     user_table, item_table,
                                                     write_emb, init_sum);
        uprev = ucur; iprev = icur;
        __half* t;
        t = ucur; ucur = ualt; ualt = t;
        t = icur; icur = ialt; ialt = t;
    }

    {
        long long tb = (long long)BATCH * 64;
        final_dot_kernel<<<(int)((tb + 255) / 256), 256, 0, stream>>>(usum, isum, u_idx, i_idx, out);
    }
}

// Round 14
// 521.411 us; speedup vs baseline: 5.1051x; 1.1181x over previous
//
#include <hip/hip_runtime.h>
#include <hip/hip_fp16.h>

#define NUM_USERS 200000
#define NUM_ITEMS 100000
#define DIM 64
#define NUM_EDGES 2000000
#define BATCH 16384
#define NUM_LAYERS 3

#define NU64 ((size_t)NUM_USERS * DIM)
#define NI64 ((size_t)NUM_ITEMS * DIM)

// bucketed CSR: user buckets = 2048-node ranges, item buckets = 1024-node ranges
#define RU_SHIFT 11
#define RI_SHIFT 10
#define NBU 98   // ceil(200000 / 2048)
#define NBI 98   // ceil(100000 / 1024)
#define CAPU 24576  // fixed capacity per bucket (expected ~20480, 28-sigma margin)
#define CAPI 24576
#define EPB 1024    // edges per scatter block

// ---------------- init (fp16 table copies) ----------------

__global__ void convert_kernel(const float4* __restrict__ ut, const float4* __restrict__ it,
                               uint2* __restrict__ uH, uint2* __restrict__ iH) {
    int idx = blockIdx.x * blockDim.x + threadIdx.x;
    const int n4u = (int)(NU64 / 4), n4i = (int)(NI64 / 4);
    if (idx < n4u) {
        float4 v = ut[idx];
        __half2 h0 = __floats2half2_rn(v.x, v.y);
        __half2 h1 = __floats2half2_rn(v.z, v.w);
        uint2 p; p.x = *(unsigned*)&h0; p.y = *(unsigned*)&h1;
        uH[idx] = p;
    } else if (idx < n4u + n4i) {
        int k = idx - n4u;
        float4 v = it[k];
        __half2 h0 = __floats2half2_rn(v.x, v.y);
        __half2 h1 = __floats2half2_rn(v.z, v.w);
        uint2 p; p.x = *(unsigned*)&h0; p.y = *(unsigned*)&h1;
        iH[k] = p;
    }
}

// ---------------- final dot: gather table + 3 layer embs at sampled rows ----------------

__global__ void final_dot_kernel(const float* __restrict__ uT, const float* __restrict__ iT,
                                 const __half* __restrict__ uE1, const __half* __restrict__ uE2,
                                 const __half* __restrict__ uE3,
                                 const __half* __restrict__ iE1, const __half* __restrict__ iE2,
                                 const __half* __restrict__ iE3,
                                 const int* __restrict__ u_idx, const int* __restrict__ i_idx,
                                 float* __restrict__ out) {
    int b    = (blockIdx.x * blockDim.x + threadIdx.x) >> 6;
    int lane = threadIdx.x & 63;
    if (b >= BATCH) return;
    int u = u_idx[b];
    int i = i_idx[b];
    size_t uo = (size_t)u * DIM + lane;
    size_t io = (size_t)i * DIM + lane;
    float su = uT[uo] + __half2float(uE1[uo]) + __half2float(uE2[uo]) + __half2float(uE3[uo]);
    float si = iT[io] + __half2float(iE1[io]) + __half2float(iE2[io]) + __half2float(iE3[io]);
    float p = su * si;
    #pragma unroll
    for (int o = 32; o > 0; o >>= 1) p += __shfl_xor(p, o, 64);
    if (lane == 0) out[b] = p * (1.0f / ((NUM_LAYERS + 1) * (NUM_LAYERS + 1)));
}

// ---------------- CSR construction v2 (no global hist, no global scan) ----------------

// Pass A: per-wave-replicated LDS binning, fixed-capacity per-bucket staging.
__global__ void bucket_scatter(const int* __restrict__ un, const int* __restrict__ in_,
                               int* __restrict__ gcurU, int* __restrict__ gcurI,
                               int2* __restrict__ stageU, int2* __restrict__ stageI) {
    __shared__ int cntU[4][NBU], cntI[4][NBI];
    __shared__ int baseU[4][NBU], baseI[4][NBI];
    int t = threadIdx.x;
    int w = t >> 6;  // wave 0..3
    for (int k = t; k < 4 * NBU; k += 256) ((int*)cntU)[k] = 0;
    for (int k = t; k < 4 * NBI; k += 256) ((int*)cntI)[k] = 0;
    __syncthreads();
    int e0 = blockIdx.x * EPB + t;
    int u[4], it[4], bu[4], bi[4], ru[4], ri[4];
    bool valid[4];
    #pragma unroll
    for (int k = 0; k < 4; ++k) {
        int e = e0 + k * 256;
        valid[k] = (e < NUM_EDGES);
        if (valid[k]) {
            u[k]  = un[e];
            it[k] = in_[e];
            bu[k] = u[k]  >> RU_SHIFT;
            bi[k] = it[k] >> RI_SHIFT;
            ru[k] = atomicAdd(&cntU[w][bu[k]], 1);
            ri[k] = atomicAdd(&cntI[w][bi[k]], 1);
        }
    }
    __syncthreads();
    if (t < NBU) {
        int c0 = cntU[0][t], c1 = cntU[1][t], c2 = cntU[2][t], c3 = cntU[3][t];
        int b = t * CAPU + atomicAdd(&gcurU[t], c0 + c1 + c2 + c3);
        baseU[0][t] = b; baseU[1][t] = b + c0; baseU[2][t] = b + c0 + c1; baseU[3][t] = b + c0 + c1 + c2;
    }
    if (t < NBI) {
        int c0 = cntI[0][t], c1 = cntI[1][t], c2 = cntI[2][t], c3 = cntI[3][t];
        int b = t * CAPI + atomicAdd(&gcurI[t], c0 + c1 + c2 + c3);
        baseI[0][t] = b; baseI[1][t] = b + c0; baseI[2][t] = b + c0 + c1; baseI[3][t] = b + c0 + c1 + c2;
    }
    __syncthreads();
    #pragma unroll
    for (int k = 0; k < 4; ++k) {
        if (valid[k]) {
            stageU[baseU[w][bu[k]] + ru[k]] = make_int2(u[k], it[k]);
            stageI[baseI[w][bi[k]] + ri[k]] = make_int2(it[k], u[k]);
        }
    }
}

// Pass B: one block per bucket. Per-node counts + LDS prefix scan produce
// offs/deg locally, then place records with LDS cursors.
__global__ void bucket_place(const int* __restrict__ gcurU, const int* __restrict__ gcurI,
                             const int2* __restrict__ stageU, const int2* __restrict__ stageI,
                             int* __restrict__ u_offs, int* __restrict__ i_offs,
                             int* __restrict__ u_deg, int* __restrict__ i_deg,
                             int* __restrict__ u_adj, int* __restrict__ i_adj) {
    __shared__ int cnt[2048];
    __shared__ int offs_l[2048];
    __shared__ int wsum[1024];
    int b = blockIdx.x, t = threadIdx.x;
    const int2* stage; int* adj; int* offs; int* deg; int lo, range, nrec, bbase;
    if (b < NBU) {
        stage = stageU + (size_t)b * CAPU; adj = u_adj; offs = u_offs; deg = u_deg;
        nrec = gcurU[b]; lo = b << RU_SHIFT; bbase = b * CAPU;
        range = NUM_USERS - lo; if (range > 2048) range = 2048;
    } else {
        int bb = b - NBU;
        stage = stageI + (size_t)bb * CAPI; adj = i_adj; offs = i_offs; deg = i_deg;
        nrec = gcurI[bb]; lo = bb << RI_SHIFT; bbase = bb * CAPI;
        range = NUM_ITEMS - lo; if (range > 1024) range = 1024;
    }
    cnt[t] = 0; cnt[t + 1024] = 0;
    __syncthreads();
    for (int r = t; r < nrec; r += 1024) atomicAdd(&cnt[stage[r].x - lo], 1);
    __syncthreads();
    int c0 = cnt[2 * t], c1 = cnt[2 * t + 1];
    int s = c0 + c1;
    wsum[t] = s;
    __syncthreads();
    for (int off = 1; off < 1024; off <<= 1) {
        int v = (t >= off) ? wsum[t - off] : 0;
        __syncthreads();
        wsum[t] += v;
        __syncthreads();
    }
    int excl = wsum[t] - s;  // exclusive prefix of node 2t
    offs_l[2 * t] = excl;
    offs_l[2 * t + 1] = excl + c0;
    if (2 * t < range)     { offs[lo + 2 * t]     = bbase + excl;      deg[lo + 2 * t]     = c0; }
    if (2 * t + 1 < range) { offs[lo + 2 * t + 1] = bbase + excl + c0; deg[lo + 2 * t + 1] = c1; }
    cnt[2 * t] = 0; cnt[2 * t + 1] = 0;   // reuse as placement cursors
    __syncthreads();
    for (int r = t; r < nrec; r += 1024) {
        int2 rec = stage[r];
        int loc = rec.x - lo;
        int p = atomicAdd(&cnt[loc], 1);
        adj[bbase + offs_l[loc] + p] = rec.y;
    }
}

// ---------------- fused pull + normalize (proven float2 structure, fp16 payload) ----------------
// One wave per row; lanes 0-31 process neighbor j, lanes 32-63 neighbor j+1,
// each lane loads __half2 (4B) = 2 dims. Accumulate/normalize f32; emb stored fp16.
// No running-sum accumulation (deferred to final_dot over sampled rows only).
__global__ void pull_norm_kernel(const int* __restrict__ u_offs, const int* __restrict__ u_deg,
                                 const int* __restrict__ u_adj,
                                 const int* __restrict__ i_offs, const int* __restrict__ i_deg,
                                 const int* __restrict__ i_adj,
                                 const __half* __restrict__ uprev, const __half* __restrict__ iprev,
                                 __half* __restrict__ unew, __half* __restrict__ inew) {
    int w    = (blockIdx.x * blockDim.x + threadIdx.x) >> 6;
    int lane = threadIdx.x & 63;
    int half = lane >> 5;   // 0 or 1
    int l32  = lane & 31;
    const int* offs; const int* deg; const int* adj; const __half* src; __half* demb; int row;
    if (w < NUM_USERS) {
        row = w; offs = u_offs; deg = u_deg; adj = u_adj; src = iprev; demb = unew;
    } else {
        row = w - NUM_USERS;
        if (row >= NUM_ITEMS) return;
        offs = i_offs; deg = i_deg; adj = i_adj; src = uprev; demb = inew;
    }
    int start = offs[row];
    int cnt   = deg[row];
    float ax = 0.0f, ay = 0.0f;
    for (int base = 0; base < cnt; base += 64) {
        int rem = cnt - base;
        if (rem > 64) rem = 64;
        int idx = (lane < rem) ? adj[start + base + lane] : 0;
        int j = 0;
        // 4 pairs (8 neighbors) per unrolled iteration
        for (; j + 8 <= rem; j += 8) {
            #pragma unroll
            for (int p = 0; p < 4; ++p) {
                int nb = __shfl(idx, j + 2 * p + half, 64);
                const __half2* srow = (const __half2*)(src + (size_t)nb * DIM);
                float2 v = __half22float2(srow[l32]);
                ax += v.x; ay += v.y;
            }
        }
        for (; j + 2 <= rem; j += 2) {
            int nb = __shfl(idx, j + half, 64);
            const __half2* srow = (const __half2*)(src + (size_t)nb * DIM);
            float2 v = __half22float2(srow[l32]);
            ax += v.x; ay += v.y;
        }
        if (j < rem) {  // odd leftover neighbor: lanes 0-31 only
            int nb = __shfl(idx, j, 64);
            const __half2* srow = (const __half2*)(src + (size_t)nb * DIM);
            float2 v = __half22float2(srow[l32]);
            if (half == 0) { ax += v.x; ay += v.y; }
        }
    }
    // merge the two half-wave partial sums
    ax += __shfl_xor(ax, 32, 64);
    ay += __shfl_xor(ay, 32, 64);
    float ss = ax * ax + ay * ay;
    #pragma unroll
    for (int o = 16; o > 0; o >>= 1) ss += __shfl_xor(ss, o, 64);
    float inv = 1.0f / fmaxf(sqrtf(ss), 1e-12f);
    float nx = ax * inv, ny = ay * inv;
    if (half == 0) {
        ((__half2*)(demb + (size_t)row * DIM))[l32] = __floats2half2_rn(nx, ny);
    }
}

// ---------------- launch ----------------

extern "C" void kernel_launch(void* const* d_in, const int* in_sizes, int n_in,
                              void* d_out, int out_size, void* d_ws, size_t ws_size,
                              hipStream_t stream) {
    const float* user_table = (const float*)d_in[0];
    const float* item_table = (const float*)d_in[1];
    const int*   u_idx      = (const int*)d_in[2];
    const int*   i_idx      = (const int*)d_in[3];
    const int*   edges      = (const int*)d_in[4];
    const int*   u_nodes    = edges;              // edge_index[0]
    const int*   i_nodes    = edges + NUM_EDGES;  // edge_index[1]
    float*       out        = (float*)d_out;

    // ---- workspace layout (~215 MB) ----
    __half* uH0 = (__half*)d_ws;        // fp16 table copy (25.6 MB)
    __half* uE1 = uH0 + NU64;           // layer-1 user emb
    __half* uE2 = uE1 + NU64;           // layer-2
    __half* uE3 = uE2 + NU64;           // layer-3
    __half* iH0 = uE3 + NU64;           // fp16 item table copy (12.8 MB)
    __half* iE1 = iH0 + NI64;
    __half* iE2 = iE1 + NI64;
    __half* iE3 = iE2 + NI64;

    int* ip     = (int*)(iE3 + NI64);
    int* u_offs = ip;                        // NUM_USERS
    int* i_offs = u_offs + NUM_USERS;        // NUM_ITEMS
    int* u_deg  = i_offs + NUM_ITEMS;        // NUM_USERS
    int* i_deg  = u_deg + NUM_USERS;         // NUM_ITEMS
    int* u_adj  = i_deg + NUM_ITEMS;         // NBU*CAPU (9.6 MB)
    int* i_adj  = u_adj + (size_t)NBU * CAPU;  // NBI*CAPI (9.6 MB)
    int* gcurU  = i_adj + (size_t)NBI * CAPI;  // NBU
    int* gcurI  = gcurU + NBU;               // NBI
    int2* stageU = (int2*)(gcurI + NBI);     // NBU*CAPU int2 (19.3 MB)
    int2* stageI = stageU + (size_t)NBU * CAPU;  // NBI*CAPI int2 (19.3 MB)

    // ---- init: fp16 copies of the tables ----
    {
        int n4 = (int)((NU64 + NI64) / 4);
        convert_kernel<<<(n4 + 255) / 256, 256, 0, stream>>>(
            (const float4*)user_table, (const float4*)item_table,
            (uint2*)uH0, (uint2*)iH0);
    }

    // ---- CSR build v2 ----
    hipMemsetAsync(gcurU, 0, (NBU + NBI) * sizeof(int), stream);

    int nblkA = (NUM_EDGES + EPB - 1) / EPB;
    bucket_scatter<<<nblkA, 256, 0, stream>>>(u_nodes, i_nodes, gcurU, gcurI, stageU, stageI);
    bucket_place<<<NBU + NBI, 1024, 0, stream>>>(gcurU, gcurI, stageU, stageI,
                                                 u_offs, i_offs, u_deg, i_deg, u_adj, i_adj);

    // ---- 3 fused pull layers (fp16 gathers; each layer's emb persisted) ----
    long long waves = (long long)(NUM_USERS + NUM_ITEMS);
    int blocks = (int)((waves * 64 + 255) / 256);
    const __half* uprevs[3] = {uH0, uE1, uE2};
    const __half* iprevs[3] = {iH0, iE1, iE2};
    __half* udsts[3] = {uE1, uE2, uE3};
    __half* idsts[3] = {iE1, iE2, iE3};
    for (int l = 0; l < NUM_LAYERS; ++l) {
        pull_norm_kernel<<<blocks, 256, 0, stream>>>(u_offs, u_deg, u_adj,
                                                     i_offs, i_deg, i_adj,
                                                     uprevs[l], iprevs[l],
                                                     udsts[l], idsts[l]);
    }

    // ---- final dot over sampled rows: (table + e1 + e2 + e3) . (table + e1 + e2 + e3) / 16 ----
    {
        long long tb = (long long)BATCH * 64;
        final_dot_kernel<<<(int)((tb + 255) / 256), 256, 0, stream>>>(
            user_table, item_table, uE1, uE2, uE3, iE1, iE2, iE3, u_idx, i_idx, out);
    }
}